// Round 6
// baseline (742.393 us; speedup 1.0000x reference)
//
#include <hip/hip_runtime.h>
#include <math.h>

#define N_NODES 50000
#define N_EDGES 800000
#define NPW 16          // nodes per wave in head kernel
#define N_STRIPS 3125   // 50000 / 16
#define N_BUCKETS 196   // ceil(50000/256), bucket = dst>>8

typedef __attribute__((ext_vector_type(8))) short bf16x8;
typedef __attribute__((ext_vector_type(4))) float f32x4;

// ---------- helpers ----------
__device__ __forceinline__ float bcast(float v, int lane) {
  return __int_as_float(__builtin_amdgcn_readlane(__float_as_int(v), lane));
}
__device__ __forceinline__ unsigned short f2bf(float f) {  // RNE f32->bf16
  unsigned int u = __float_as_uint(f);
  u += 0x7FFFu + ((u >> 16) & 1u);
  return (unsigned short)(u >> 16);
}
__device__ __forceinline__ float bf2f(unsigned short s) {
  return __uint_as_float(((unsigned int)s) << 16);
}
__device__ __forceinline__ float bfLO(unsigned int u) {
  return __uint_as_float(u << 16);
}
__device__ __forceinline__ float bfHI(unsigned int u) {
  return __uint_as_float(u & 0xFFFF0000u);
}

// ---------- 1. input projection ----------
__global__ __launch_bounds__(256) void k_proj(const float* __restrict__ x,
                                              const float* __restrict__ Wp,
                                              const float* __restrict__ bp,
                                              float* __restrict__ h,
                                              unsigned short* __restrict__ hb) {
  int idx = blockIdx.x * 256 + threadIdx.x;
  int n = idx >> 6, j = idx & 63;
  if (n >= N_NODES) return;
  float acc = bp[j];
#pragma unroll
  for (int k = 0; k < 10; k++) acc += x[n * 10 + k] * Wp[k * 64 + j];
  float r = fmaxf(acc, 0.f);
  h[n * 64 + j] = r;
  hb[n * 64 + j] = f2bf(r);
}

// ---------- 2. CSR build: histogram + scan ----------
__global__ __launch_bounds__(256) void k_hist(const int* __restrict__ ei, int* __restrict__ deg) {
  int e = blockIdx.x * 256 + threadIdx.x;
  if (e >= N_EDGES) return;
  atomicAdd(&deg[ei[N_EDGES + e]], 1);
}

__global__ __launch_bounds__(256) void k_scan1(const int* __restrict__ deg,
                                               int* __restrict__ offs,
                                               int* __restrict__ bsums) {
  __shared__ int sm[256];
  int i = blockIdx.x * 256 + threadIdx.x;
  int v = (i < N_NODES) ? deg[i] : 0;
  sm[threadIdx.x] = v;
  __syncthreads();
#pragma unroll
  for (int off = 1; off < 256; off <<= 1) {
    int t = (threadIdx.x >= off) ? sm[threadIdx.x - off] : 0;
    __syncthreads();
    sm[threadIdx.x] += t;
    __syncthreads();
  }
  if (i < N_NODES) offs[i] = sm[threadIdx.x] - v;  // exclusive
  if (threadIdx.x == 255) bsums[blockIdx.x] = sm[255];
}

__global__ __launch_bounds__(256) void k_scan2(int* __restrict__ bsums, int nb) {
  __shared__ int sm[256];
  int t = threadIdx.x;
  int v = (t < nb) ? bsums[t] : 0;
  sm[t] = v;
  __syncthreads();
#pragma unroll
  for (int off = 1; off < 256; off <<= 1) {
    int u = (t >= off) ? sm[t - off] : 0;
    __syncthreads();
    sm[t] += u;
    __syncthreads();
  }
  if (t < nb) bsums[t] = sm[t] - v;  // exclusive
}

__global__ __launch_bounds__(256) void k_scan3(int* __restrict__ offs,
                                               const int* __restrict__ bsums,
                                               int* __restrict__ cursor) {
  int i = blockIdx.x * 256 + threadIdx.x;
  if (i >= N_NODES) return;
  int o = offs[i] + bsums[blockIdx.x];
  offs[i] = o;
  cursor[i] = o;
}

// bucket cursors: bcur[b] = offs[b*256]  (bucket b covers dst in [b*256,(b+1)*256))
__global__ __launch_bounds__(256) void k_binit(const int* __restrict__ offs,
                                               int* __restrict__ bcur) {
  int b = threadIdx.x;
  if (b < N_BUCKETS) bcur[b] = offs[b * 256];
}

// ---------- pass 1: edge MLP + append to dst-range bucket (dense write frontier)
// record: x = src(17b) | q0<<17 (13b) | (dstlow>>6)<<30
//         y = q1 (13b) | q2<<13 (13b) | (dstlow&63)<<26
__global__ __launch_bounds__(256) void k_fill1(const int* __restrict__ ei,
                                               const float* __restrict__ ea,
                                               const float* __restrict__ ew1,
                                               const float* __restrict__ eb1,
                                               const float* __restrict__ ew2,
                                               const float* __restrict__ eb2,
                                               int* __restrict__ bcur,
                                               uint2* __restrict__ buf1) {
  int e = blockIdx.x * 256 + threadIdx.x;
  if (e >= N_EDGES) return;
  int s = ei[e];
  int d = ei[N_EDGES + e];
  float a0 = ea[e * 3 + 0], a1 = ea[e * 3 + 1], a2 = ea[e * 3 + 2];
  int q[3];
#pragma unroll
  for (int l = 0; l < 3; l++) {
    float z = eb2[l];
#pragma unroll
    for (int t = 0; t < 16; t++) {
      float hd = a0 * ew1[l * 48 + t] + a1 * ew1[l * 48 + 16 + t] +
                 a2 * ew1[l * 48 + 32 + t] + eb1[l * 16 + t];
      z += fmaxf(hd, 0.f) * ew2[l * 16 + t];
    }
    float w = 1.f / (1.f + __expf(-z));
    q[l] = __float2int_rn(w * 8191.f);
  }
  unsigned int dl = (unsigned int)(d & 255);
  unsigned int rx = (unsigned int)s | ((unsigned int)q[0] << 17) | ((dl >> 6) << 30);
  unsigned int ry = (unsigned int)q[1] | ((unsigned int)q[2] << 13) | ((dl & 63u) << 26);
  int pos = atomicAdd(&bcur[d >> 8], 1);
  buf1[pos] = make_uint2(rx, ry);
}

// ---------- pass 2: bucket -> exact CSR position (scatter within ~32KB window)
__global__ __launch_bounds__(256) void k_fill2(const uint2* __restrict__ buf1,
                                               const int* __restrict__ offs,
                                               int* __restrict__ cursor,
                                               uint2* __restrict__ csr) {
  __shared__ int bo[N_BUCKETS + 1];
  for (int i = threadIdx.x; i <= N_BUCKETS; i += 256)
    bo[i] = (i < N_BUCKETS) ? offs[i * 256] : N_EDGES;
  __syncthreads();
  int p = blockIdx.x * 256 + threadIdx.x;
  if (p >= N_EDGES) return;
  uint2 rec = buf1[p];
  int lo = 0, hi = N_BUCKETS;
#pragma unroll
  for (int it = 0; it < 8; it++) {  // 2^8 >= 197
    int mid = (lo + hi) >> 1;
    if (bo[mid] <= p) lo = mid; else hi = mid;
  }
  int dl = (int)(((rec.x >> 30) << 6) | ((rec.y >> 26) & 63u));
  int d = (lo << 8) | dl;
  int pos = atomicAdd(&cursor[d], 1);
  csr[pos] = rec;
}

template <int LI>
__device__ __forceinline__ float decw(uint2 c) {
  unsigned int q = (LI == 0) ? ((c.x >> 17) & 0x1FFFu)
                 : (LI == 1) ? (c.y & 0x1FFFu)
                             : ((c.y >> 13) & 0x1FFFu);
  return (float)q * (1.f / 8191.f);
}

// ---------- 3. aggregation: 4 nodes/wave (16 lanes/node, 4 feats/lane) ----------
template <int LI>
__global__ __launch_bounds__(256, 8) void k_agg(const uint2* __restrict__ csr,
                                                const int* __restrict__ offs,
                                                const int* __restrict__ deg,
                                                const unsigned short* __restrict__ hbin,
                                                unsigned short* __restrict__ ab) {
  int lane = threadIdx.x & 63;
  int sub = lane >> 4;
  int jj = lane & 15;
  int gw = (blockIdx.x * 256 + threadIdx.x) >> 6;
  int n = gw * 4 + sub;
  bool active = n < N_NODES;
  int start = active ? offs[n] : 0;
  int d = active ? deg[n] : 0;
  const uint2* hrow = (const uint2*)hbin;
  float a0 = 0.f, a1 = 0.f, a2 = 0.f, a3 = 0.f, ws = 0.f;
  int i = 0;
  for (; i + 4 <= d; i += 4) {
    uint2 c0 = csr[start + i + 0];
    uint2 c1 = csr[start + i + 1];
    uint2 c2 = csr[start + i + 2];
    uint2 c3 = csr[start + i + 3];
    uint2 g0 = hrow[(c0.x & 0x1FFFFu) * 16 + jj];
    uint2 g1 = hrow[(c1.x & 0x1FFFFu) * 16 + jj];
    uint2 g2 = hrow[(c2.x & 0x1FFFFu) * 16 + jj];
    uint2 g3 = hrow[(c3.x & 0x1FFFFu) * 16 + jj];
    float w0 = decw<LI>(c0), w1 = decw<LI>(c1), w2 = decw<LI>(c2), w3 = decw<LI>(c3);
    a0 += bfLO(g0.x) * w0 + bfLO(g1.x) * w1 + bfLO(g2.x) * w2 + bfLO(g3.x) * w3;
    a1 += bfHI(g0.x) * w0 + bfHI(g1.x) * w1 + bfHI(g2.x) * w2 + bfHI(g3.x) * w3;
    a2 += bfLO(g0.y) * w0 + bfLO(g1.y) * w1 + bfLO(g2.y) * w2 + bfLO(g3.y) * w3;
    a3 += bfHI(g0.y) * w0 + bfHI(g1.y) * w1 + bfHI(g2.y) * w2 + bfHI(g3.y) * w3;
    ws += w0 + w1 + w2 + w3;
  }
  for (; i < d; ++i) {
    uint2 c = csr[start + i];
    uint2 g = hrow[(c.x & 0x1FFFFu) * 16 + jj];
    float w = decw<LI>(c);
    a0 += bfLO(g.x) * w;
    a1 += bfHI(g.x) * w;
    a2 += bfLO(g.y) * w;
    a3 += bfHI(g.y) * w;
    ws += w;
  }
  if (active) {
    float inv = fmaxf(ws, 1e-12f);
    a0 /= inv; a1 /= inv; a2 /= inv; a3 /= inv;
    unsigned int u0 = (unsigned int)f2bf(a0) | ((unsigned int)f2bf(a1) << 16);
    unsigned int u1 = (unsigned int)f2bf(a2) | ((unsigned int)f2bf(a3) << 16);
    ((uint2*)ab)[n * 16 + jj] = make_uint2(u0, u1);
  }
}

// ---------- 4. node MLP (MFMA) + residual + LayerNorm ----------
__global__ __launch_bounds__(256) void k_mlp(const float* __restrict__ nw,
                                             const float* __restrict__ nb,
                                             const float* __restrict__ g,
                                             const float* __restrict__ b,
                                             const float* __restrict__ hin,
                                             const unsigned short* __restrict__ hb_in,
                                             const unsigned short* __restrict__ ab_in,
                                             float* __restrict__ hout,
                                             unsigned short* __restrict__ hbout) {
  int lane = threadIdx.x & 63;
  int n16 = lane & 15;
  int q = lane >> 4;
  int wid = (blockIdx.x * 256 + threadIdx.x) >> 6;
  int nwaves = gridDim.x * 4;

  bf16x8 bfr[4][4];
#pragma unroll
  for (int t = 0; t < 4; t++)
#pragma unroll
    for (int kc = 0; kc < 4; kc++) {
      bf16x8 v;
#pragma unroll
      for (int jj = 0; jj < 8; jj++) {
        int k = kc * 32 + q * 8 + jj;
        v[jj] = (short)f2bf(nw[k * 64 + t * 16 + n16]);
      }
      bfr[t][kc] = v;
    }
  float nbv[4], gv[4], bv[4];
#pragma unroll
  for (int t = 0; t < 4; t++) {
    nbv[t] = nb[t * 16 + n16];
    gv[t] = g[t * 16 + n16];
    bv[t] = b[t * 16 + n16];
  }

  for (int s = wid; s < N_STRIPS; s += nwaves) {
    int n0 = s * 16;
    f32x4 acc[4] = {{0.f, 0.f, 0.f, 0.f}, {0.f, 0.f, 0.f, 0.f},
                    {0.f, 0.f, 0.f, 0.f}, {0.f, 0.f, 0.f, 0.f}};
#pragma unroll
    for (int kc = 0; kc < 4; kc++) {
      const unsigned short* base = (kc < 2) ? hb_in : ab_in;
      bf16x8 a = *(const bf16x8*)(base + (size_t)(n0 + n16) * 64 + (kc & 1) * 32 + q * 8);
#pragma unroll
      for (int t = 0; t < 4; t++)
        acc[t] = __builtin_amdgcn_mfma_f32_16x16x32_bf16(a, bfr[t][kc], acc[t], 0, 0, 0);
    }
    float r[4][4];
    float p[4], p2[4];
#pragma unroll
    for (int rg = 0; rg < 4; rg++) { p[rg] = 0.f; p2[rg] = 0.f; }
#pragma unroll
    for (int t = 0; t < 4; t++)
#pragma unroll
      for (int rg = 0; rg < 4; rg++) {
        int row = n0 + q * 4 + rg;
        float hv = hin[row * 64 + t * 16 + n16];
        float rr = hv + fmaxf(acc[t][rg] + nbv[t], 0.f);
        r[t][rg] = rr;
        p[rg] += rr;
        p2[rg] += rr * rr;
      }
#pragma unroll
    for (int rg = 0; rg < 4; rg++)
#pragma unroll
      for (int off = 1; off < 16; off <<= 1) {
        p[rg] += __shfl_xor(p[rg], off);
        p2[rg] += __shfl_xor(p2[rg], off);
      }
#pragma unroll
    for (int rg = 0; rg < 4; rg++) {
      float mu = p[rg] * (1.f / 64.f);
      float var = p2[rg] * (1.f / 64.f) - mu * mu;
      float rs = rsqrtf(fmaxf(var, 0.f) + 1e-5f);
      int row = n0 + q * 4 + rg;
#pragma unroll
      for (int t = 0; t < 4; t++) {
        float o = (r[t][rg] - mu) * rs * gv[t] + bv[t];
        hout[row * 64 + t * 16 + n16] = o;
        hbout[row * 64 + t * 16 + n16] = f2bf(o);
      }
    }
  }
}

// ---------- 5. head ----------
__global__ __launch_bounds__(256, 2) void k_head(const float* __restrict__ hw1,
                                                 const float* __restrict__ hb1,
                                                 const float* __restrict__ hw2,
                                                 const float* __restrict__ hb2,
                                                 const float* __restrict__ hin,
                                                 float* __restrict__ out) {
  int j = threadIdx.x & 63;
  int jj = j & 31;
  int gw = (blockIdx.x * 256 + threadIdx.x) >> 6;
  float w1[64];
#pragma unroll
  for (int k = 0; k < 64; k++) w1[k] = hw1[k * 32 + jj];
  float hb1j = hb1[jj];
  float hw2j = hw2[jj];
  float hb2v = hb2[0];
  int n0 = gw * NPW;
  for (int n = n0; n < n0 + NPW; ++n) {
    if (n >= N_NODES) break;
    float hv = hin[n * 64 + j];
    float acc = hb1j;
#pragma unroll
    for (int k = 0; k < 64; k++) acc += bcast(hv, k) * w1[k];
    float z = fmaxf(acc, 0.f) * hw2j;
    if (j >= 32) z = 0.f;
#pragma unroll
    for (int off = 32; off; off >>= 1) z += __shfl_xor(z, off);
    if (j == 0) out[n] = z + hb2v;
  }
}

// ---------- launch ----------
static inline size_t align256(size_t x) { return (x + 255) & ~size_t(255); }

extern "C" void kernel_launch(void* const* d_in, const int* in_sizes, int n_in,
                              void* d_out, int out_size, void* d_ws, size_t ws_size,
                              hipStream_t stream) {
  const float* x   = (const float*)d_in[0];
  const int*   ei  = (const int*)d_in[1];
  const float* ea  = (const float*)d_in[2];
  const float* Wp  = (const float*)d_in[3];
  const float* bp  = (const float*)d_in[4];
  const float* ew1 = (const float*)d_in[5];
  const float* eb1 = (const float*)d_in[6];
  const float* ew2 = (const float*)d_in[7];
  const float* eb2 = (const float*)d_in[8];
  const float* nw  = (const float*)d_in[9];
  const float* nb  = (const float*)d_in[10];
  const float* lng = (const float*)d_in[11];
  const float* lnb = (const float*)d_in[12];
  const float* hw1 = (const float*)d_in[13];
  const float* hb1 = (const float*)d_in[14];
  const float* hw2 = (const float*)d_in[15];
  const float* hb2 = (const float*)d_in[16];
  float* out = (float*)d_out;

  char* ws = (char*)d_ws;
  size_t off = 0;
  float* h0f = (float*)(ws + off); off = align256(off + (size_t)N_NODES * 64 * 4);
  float* h1f = (float*)(ws + off); off = align256(off + (size_t)N_NODES * 64 * 4);
  unsigned short* hb0  = (unsigned short*)(ws + off); off = align256(off + (size_t)N_NODES * 64 * 2);
  unsigned short* hb1b = (unsigned short*)(ws + off); off = align256(off + (size_t)N_NODES * 64 * 2);
  unsigned short* ab   = (unsigned short*)(ws + off); off = align256(off + (size_t)N_NODES * 64 * 2);
  uint2* csr  = (uint2*)(ws + off); off = align256(off + (size_t)N_EDGES * 8);
  uint2* buf1 = (uint2*)(ws + off); off = align256(off + (size_t)N_EDGES * 8);
  int* deg    = (int*)(ws + off); off = align256(off + (size_t)N_NODES * 4);
  int* offs   = (int*)(ws + off); off = align256(off + (size_t)N_NODES * 4);
  int* cursor = (int*)(ws + off); off = align256(off + (size_t)N_NODES * 4);
  int* bcur   = (int*)(ws + off); off = align256(off + 1024);
  int* bsums  = (int*)(ws + off); off = align256(off + 1024);

  const int NB_SCAN = (N_NODES + 255) / 256;  // 196

  hipMemsetAsync(deg, 0, (size_t)N_NODES * 4, stream);

  k_proj<<<(N_NODES * 64 + 255) / 256, 256, 0, stream>>>(x, Wp, bp, h0f, hb0);
  k_hist<<<(N_EDGES + 255) / 256, 256, 0, stream>>>(ei, deg);
  k_scan1<<<NB_SCAN, 256, 0, stream>>>(deg, offs, bsums);
  k_scan2<<<1, 256, 0, stream>>>(bsums, NB_SCAN);
  k_scan3<<<NB_SCAN, 256, 0, stream>>>(offs, bsums, cursor);
  k_binit<<<1, 256, 0, stream>>>(offs, bcur);

  const int edgeGrid = (N_EDGES + 255) / 256;  // 3125
  k_fill1<<<edgeGrid, 256, 0, stream>>>(ei, ea, ew1, eb1, ew2, eb2, bcur, buf1);
  k_fill2<<<edgeGrid, 256, 0, stream>>>(buf1, offs, cursor, csr);

  const int aggGrid = (N_NODES + 7) / 8;  // 4 nodes/wave, 4 waves/block
  const int mlpGrid = 392;
  const int headGrid = ((N_NODES + NPW - 1) / NPW + 3) / 4;

  // layer 0: h0 -> h1
  k_agg<0><<<aggGrid, 256, 0, stream>>>(csr, offs, deg, hb0, ab);
  k_mlp<<<mlpGrid, 256, 0, stream>>>(nw + 0 * 8192, nb + 0 * 64, lng + 0 * 64, lnb + 0 * 64,
                                     h0f, hb0, ab, h1f, hb1b);
  // layer 1: h1 -> h0
  k_agg<1><<<aggGrid, 256, 0, stream>>>(csr, offs, deg, hb1b, ab);
  k_mlp<<<mlpGrid, 256, 0, stream>>>(nw + 1 * 8192, nb + 1 * 64, lng + 1 * 64, lnb + 1 * 64,
                                     h1f, hb1b, ab, h0f, hb0);
  // layer 2: h0 -> h1
  k_agg<2><<<aggGrid, 256, 0, stream>>>(csr, offs, deg, hb0, ab);
  k_mlp<<<mlpGrid, 256, 0, stream>>>(nw + 2 * 8192, nb + 2 * 64, lng + 2 * 64, lnb + 2 * 64,
                                     h0f, hb0, ab, h1f, hb1b);

  k_head<<<headGrid, 256, 0, stream>>>(hw1, hb1, hw2, hb2, h1f, out);
}

// Round 7
// 296.437 us; speedup vs baseline: 2.5044x; 2.5044x over previous
//
#include <hip/hip_runtime.h>
#include <math.h>

#define N_NODES 50000
#define N_EDGES 800000
#define NPW 16          // nodes per wave in head kernel
#define N_STRIPS 3125   // 50000 / 16

typedef __attribute__((ext_vector_type(8))) short bf16x8;
typedef __attribute__((ext_vector_type(4))) float f32x4;

// ---------- helpers ----------
__device__ __forceinline__ float bcast(float v, int lane) {
  return __int_as_float(__builtin_amdgcn_readlane(__float_as_int(v), lane));
}
__device__ __forceinline__ unsigned short f2bf(float f) {  // RNE f32->bf16
  unsigned int u = __float_as_uint(f);
  u += 0x7FFFu + ((u >> 16) & 1u);
  return (unsigned short)(u >> 16);
}
__device__ __forceinline__ float bf2f(unsigned short s) {
  return __uint_as_float(((unsigned int)s) << 16);
}
__device__ __forceinline__ float bfLO(unsigned int u) {
  return __uint_as_float(u << 16);
}
__device__ __forceinline__ float bfHI(unsigned int u) {
  return __uint_as_float(u & 0xFFFF0000u);
}

// ---------- 1. input projection: h = relu(x @ Wp + bp), bf16 out ----------
__global__ __launch_bounds__(256) void k_proj(const float* __restrict__ x,
                                              const float* __restrict__ Wp,
                                              const float* __restrict__ bp,
                                              unsigned short* __restrict__ hb) {
  int idx = blockIdx.x * 256 + threadIdx.x;
  int n = idx >> 6, j = idx & 63;
  if (n >= N_NODES) return;
  float acc = bp[j];
#pragma unroll
  for (int k = 0; k < 10; k++) acc += x[n * 10 + k] * Wp[k * 64 + j];
  hb[n * 64 + j] = f2bf(fmaxf(acc, 0.f));
}

// ---------- 2. CSR build ----------
__global__ __launch_bounds__(256) void k_hist(const int* __restrict__ ei, int* __restrict__ deg) {
  int e = blockIdx.x * 256 + threadIdx.x;
  if (e >= N_EDGES) return;
  atomicAdd(&deg[ei[N_EDGES + e]], 1);
}

__global__ __launch_bounds__(256) void k_scan1(const int* __restrict__ deg,
                                               int* __restrict__ offs,
                                               int* __restrict__ bsums) {
  __shared__ int sm[256];
  int i = blockIdx.x * 256 + threadIdx.x;
  int v = (i < N_NODES) ? deg[i] : 0;
  sm[threadIdx.x] = v;
  __syncthreads();
#pragma unroll
  for (int off = 1; off < 256; off <<= 1) {
    int t = (threadIdx.x >= off) ? sm[threadIdx.x - off] : 0;
    __syncthreads();
    sm[threadIdx.x] += t;
    __syncthreads();
  }
  if (i < N_NODES) offs[i] = sm[threadIdx.x] - v;  // exclusive
  if (threadIdx.x == 255) bsums[blockIdx.x] = sm[255];
}

__global__ __launch_bounds__(256) void k_scan2(int* __restrict__ bsums, int nb) {
  __shared__ int sm[256];
  int t = threadIdx.x;
  int v = (t < nb) ? bsums[t] : 0;
  sm[t] = v;
  __syncthreads();
#pragma unroll
  for (int off = 1; off < 256; off <<= 1) {
    int u = (t >= off) ? sm[t - off] : 0;
    __syncthreads();
    sm[t] += u;
    __syncthreads();
  }
  if (t < nb) bsums[t] = sm[t] - v;  // exclusive
}

__global__ __launch_bounds__(256) void k_scan3(int* __restrict__ offs,
                                               const int* __restrict__ bsums,
                                               int* __restrict__ cursor) {
  int i = blockIdx.x * 256 + threadIdx.x;
  if (i >= N_NODES) return;
  int o = offs[i] + bsums[blockIdx.x];
  offs[i] = o;
  cursor[i] = o;
}

// single-pass fill (R4 structure — 50k-address cursor atomics, known ~55us).
// 8B record: x = src(17b) | q0<<17 (15b) ; y = q1 | q2<<15 (15b each)
__global__ __launch_bounds__(256) void k_fill(const int* __restrict__ ei,
                                              const float* __restrict__ ea,
                                              const float* __restrict__ ew1,
                                              const float* __restrict__ eb1,
                                              const float* __restrict__ ew2,
                                              const float* __restrict__ eb2,
                                              int* __restrict__ cursor,
                                              uint2* __restrict__ csr) {
  int e = blockIdx.x * 256 + threadIdx.x;
  if (e >= N_EDGES) return;
  int s = ei[e];
  int d = ei[N_EDGES + e];
  float a0 = ea[e * 3 + 0], a1 = ea[e * 3 + 1], a2 = ea[e * 3 + 2];
  int q[3];
#pragma unroll
  for (int l = 0; l < 3; l++) {
    float z = eb2[l];
#pragma unroll
    for (int t = 0; t < 16; t++) {
      float hd = a0 * ew1[l * 48 + t] + a1 * ew1[l * 48 + 16 + t] +
                 a2 * ew1[l * 48 + 32 + t] + eb1[l * 16 + t];
      z += fmaxf(hd, 0.f) * ew2[l * 16 + t];
    }
    float w = 1.f / (1.f + __expf(-z));
    q[l] = __float2int_rn(w * 32767.f);
  }
  unsigned int w0 = (unsigned int)s | ((unsigned int)q[0] << 17);
  unsigned int w1 = (unsigned int)q[1] | ((unsigned int)q[2] << 15);
  int pos = atomicAdd(&cursor[d], 1);
  csr[pos] = make_uint2(w0, w1);
}

template <int LI>
__device__ __forceinline__ float decw(uint2 c) {
  unsigned int q = (LI == 0) ? (c.x >> 17) : (LI == 1) ? (c.y & 0x7FFFu) : (c.y >> 15);
  return (float)q * (1.f / 32767.f);
}

// ---------- 3. aggregation: 8 nodes/wave, 8 lanes/node, uint4 (16B) gathers ----------
// 32 gather loads in flight per wave; full row coalescing (8 lanes x 16B = 128B).
template <int LI>
__global__ __launch_bounds__(256, 8) void k_agg(const uint2* __restrict__ csr,
                                                const int* __restrict__ offs,
                                                const int* __restrict__ deg,
                                                const unsigned short* __restrict__ hbin,
                                                unsigned short* __restrict__ ab) {
  int lane = threadIdx.x & 63;
  int sub = lane >> 3;   // node slot 0..7
  int jj = lane & 7;     // feature octet: features [8jj, 8jj+8)
  int gw = (blockIdx.x * 256 + threadIdx.x) >> 6;
  int n = gw * 8 + sub;
  bool active = n < N_NODES;
  int start = active ? offs[n] : 0;
  int d = active ? deg[n] : 0;
  const uint4* hrow = (const uint4*)hbin;  // row n at hrow[n*8 + jj]
  float a0 = 0.f, a1 = 0.f, a2 = 0.f, a3 = 0.f;
  float a4 = 0.f, a5 = 0.f, a6 = 0.f, a7 = 0.f, ws = 0.f;
  int i = 0;
  for (; i + 4 <= d; i += 4) {
    uint2 c0 = csr[start + i + 0];
    uint2 c1 = csr[start + i + 1];
    uint2 c2 = csr[start + i + 2];
    uint2 c3 = csr[start + i + 3];
    uint4 g0 = hrow[(c0.x & 0x1FFFFu) * 8 + jj];
    uint4 g1 = hrow[(c1.x & 0x1FFFFu) * 8 + jj];
    uint4 g2 = hrow[(c2.x & 0x1FFFFu) * 8 + jj];
    uint4 g3 = hrow[(c3.x & 0x1FFFFu) * 8 + jj];
    float w0 = decw<LI>(c0), w1 = decw<LI>(c1), w2 = decw<LI>(c2), w3 = decw<LI>(c3);
    a0 += bfLO(g0.x) * w0 + bfLO(g1.x) * w1 + bfLO(g2.x) * w2 + bfLO(g3.x) * w3;
    a1 += bfHI(g0.x) * w0 + bfHI(g1.x) * w1 + bfHI(g2.x) * w2 + bfHI(g3.x) * w3;
    a2 += bfLO(g0.y) * w0 + bfLO(g1.y) * w1 + bfLO(g2.y) * w2 + bfLO(g3.y) * w3;
    a3 += bfHI(g0.y) * w0 + bfHI(g1.y) * w1 + bfHI(g2.y) * w2 + bfHI(g3.y) * w3;
    a4 += bfLO(g0.z) * w0 + bfLO(g1.z) * w1 + bfLO(g2.z) * w2 + bfLO(g3.z) * w3;
    a5 += bfHI(g0.z) * w0 + bfHI(g1.z) * w1 + bfHI(g2.z) * w2 + bfHI(g3.z) * w3;
    a6 += bfLO(g0.w) * w0 + bfLO(g1.w) * w1 + bfLO(g2.w) * w2 + bfLO(g3.w) * w3;
    a7 += bfHI(g0.w) * w0 + bfHI(g1.w) * w1 + bfHI(g2.w) * w2 + bfHI(g3.w) * w3;
    ws += w0 + w1 + w2 + w3;
  }
  for (; i < d; ++i) {
    uint2 c = csr[start + i];
    uint4 g = hrow[(c.x & 0x1FFFFu) * 8 + jj];
    float w = decw<LI>(c);
    a0 += bfLO(g.x) * w; a1 += bfHI(g.x) * w;
    a2 += bfLO(g.y) * w; a3 += bfHI(g.y) * w;
    a4 += bfLO(g.z) * w; a5 += bfHI(g.z) * w;
    a6 += bfLO(g.w) * w; a7 += bfHI(g.w) * w;
    ws += w;
  }
  if (active) {
    float inv = 1.f / fmaxf(ws, 1e-12f);
    uint4 o;
    o.x = (unsigned int)f2bf(a0 * inv) | ((unsigned int)f2bf(a1 * inv) << 16);
    o.y = (unsigned int)f2bf(a2 * inv) | ((unsigned int)f2bf(a3 * inv) << 16);
    o.z = (unsigned int)f2bf(a4 * inv) | ((unsigned int)f2bf(a5 * inv) << 16);
    o.w = (unsigned int)f2bf(a6 * inv) | ((unsigned int)f2bf(a7 * inv) << 16);
    ((uint4*)ab)[n * 8 + jj] = o;
  }
}

// ---------- 4. node MLP (MFMA) + residual + LayerNorm, all-bf16 h ----------
// C(50000x64) = [hb | ab](50000x128, bf16) @ nw(128x64, cast bf16)
// C/D layout: col=lane&15, row=(lane>>4)*4+reg ; A/B frag: k=(lane>>4)*8+j
__global__ __launch_bounds__(256) void k_mlp(const float* __restrict__ nw,
                                             const float* __restrict__ nb,
                                             const float* __restrict__ g,
                                             const float* __restrict__ b,
                                             const unsigned short* __restrict__ hb_in,
                                             const unsigned short* __restrict__ ab_in,
                                             unsigned short* __restrict__ hbout) {
  int lane = threadIdx.x & 63;
  int n16 = lane & 15;
  int q = lane >> 4;
  int wid = (blockIdx.x * 256 + threadIdx.x) >> 6;
  int nwaves = gridDim.x * 4;

  bf16x8 bfr[4][4];
#pragma unroll
  for (int t = 0; t < 4; t++)
#pragma unroll
    for (int kc = 0; kc < 4; kc++) {
      bf16x8 v;
#pragma unroll
      for (int jj = 0; jj < 8; jj++) {
        int k = kc * 32 + q * 8 + jj;
        v[jj] = (short)f2bf(nw[k * 64 + t * 16 + n16]);
      }
      bfr[t][kc] = v;
    }
  float nbv[4], gv[4], bv[4];
#pragma unroll
  for (int t = 0; t < 4; t++) {
    nbv[t] = nb[t * 16 + n16];
    gv[t] = g[t * 16 + n16];
    bv[t] = b[t * 16 + n16];
  }

  for (int s = wid; s < N_STRIPS; s += nwaves) {
    int n0 = s * 16;
    f32x4 acc[4] = {{0.f, 0.f, 0.f, 0.f}, {0.f, 0.f, 0.f, 0.f},
                    {0.f, 0.f, 0.f, 0.f}, {0.f, 0.f, 0.f, 0.f}};
#pragma unroll
    for (int kc = 0; kc < 4; kc++) {
      const unsigned short* base = (kc < 2) ? hb_in : ab_in;
      bf16x8 a = *(const bf16x8*)(base + (size_t)(n0 + n16) * 64 + (kc & 1) * 32 + q * 8);
#pragma unroll
      for (int t = 0; t < 4; t++)
        acc[t] = __builtin_amdgcn_mfma_f32_16x16x32_bf16(a, bfr[t][kc], acc[t], 0, 0, 0);
    }
    float r[4][4];
    float p[4], p2[4];
#pragma unroll
    for (int rg = 0; rg < 4; rg++) { p[rg] = 0.f; p2[rg] = 0.f; }
#pragma unroll
    for (int t = 0; t < 4; t++)
#pragma unroll
      for (int rg = 0; rg < 4; rg++) {
        int row = n0 + q * 4 + rg;
        float hv = bf2f(hb_in[row * 64 + t * 16 + n16]);
        float rr = hv + fmaxf(acc[t][rg] + nbv[t], 0.f);
        r[t][rg] = rr;
        p[rg] += rr;
        p2[rg] += rr * rr;
      }
#pragma unroll
    for (int rg = 0; rg < 4; rg++)
#pragma unroll
      for (int off = 1; off < 16; off <<= 1) {
        p[rg] += __shfl_xor(p[rg], off);
        p2[rg] += __shfl_xor(p2[rg], off);
      }
#pragma unroll
    for (int rg = 0; rg < 4; rg++) {
      float mu = p[rg] * (1.f / 64.f);
      float var = p2[rg] * (1.f / 64.f) - mu * mu;
      float rs = rsqrtf(fmaxf(var, 0.f) + 1e-5f);
      int row = n0 + q * 4 + rg;
#pragma unroll
      for (int t = 0; t < 4; t++) {
        float o = (r[t][rg] - mu) * rs * gv[t] + bv[t];
        hbout[row * 64 + t * 16 + n16] = f2bf(o);
      }
    }
  }
}

// ---------- 5. head: out = relu(h@hw1+hb1)@hw2 + hb2 (bf16 h in) ----------
__global__ __launch_bounds__(256, 2) void k_head(const float* __restrict__ hw1,
                                                 const float* __restrict__ hb1,
                                                 const float* __restrict__ hw2,
                                                 const float* __restrict__ hb2,
                                                 const unsigned short* __restrict__ hin,
                                                 float* __restrict__ out) {
  int j = threadIdx.x & 63;
  int jj = j & 31;
  int gw = (blockIdx.x * 256 + threadIdx.x) >> 6;
  float w1[64];
#pragma unroll
  for (int k = 0; k < 64; k++) w1[k] = hw1[k * 32 + jj];
  float hb1j = hb1[jj];
  float hw2j = hw2[jj];
  float hb2v = hb2[0];
  int n0 = gw * NPW;
  for (int n = n0; n < n0 + NPW; ++n) {
    if (n >= N_NODES) break;
    float hv = bf2f(hin[n * 64 + j]);
    float acc = hb1j;
#pragma unroll
    for (int k = 0; k < 64; k++) acc += bcast(hv, k) * w1[k];
    float z = fmaxf(acc, 0.f) * hw2j;
    if (j >= 32) z = 0.f;  // upper 32 lanes duplicate lower-half columns
#pragma unroll
    for (int off = 32; off; off >>= 1) z += __shfl_xor(z, off);
    if (j == 0) out[n] = z + hb2v;
  }
}

// ---------- launch ----------
static inline size_t align256(size_t x) { return (x + 255) & ~size_t(255); }

extern "C" void kernel_launch(void* const* d_in, const int* in_sizes, int n_in,
                              void* d_out, int out_size, void* d_ws, size_t ws_size,
                              hipStream_t stream) {
  const float* x   = (const float*)d_in[0];
  const int*   ei  = (const int*)d_in[1];
  const float* ea  = (const float*)d_in[2];
  const float* Wp  = (const float*)d_in[3];
  const float* bp  = (const float*)d_in[4];
  const float* ew1 = (const float*)d_in[5];
  const float* eb1 = (const float*)d_in[6];
  const float* ew2 = (const float*)d_in[7];
  const float* eb2 = (const float*)d_in[8];
  const float* nw  = (const float*)d_in[9];
  const float* nb  = (const float*)d_in[10];
  const float* lng = (const float*)d_in[11];
  const float* lnb = (const float*)d_in[12];
  const float* hw1 = (const float*)d_in[13];
  const float* hb1 = (const float*)d_in[14];
  const float* hw2 = (const float*)d_in[15];
  const float* hb2 = (const float*)d_in[16];
  float* out = (float*)d_out;

  char* ws = (char*)d_ws;
  size_t off = 0;
  unsigned short* hb0  = (unsigned short*)(ws + off); off = align256(off + (size_t)N_NODES * 64 * 2);
  unsigned short* hb1b = (unsigned short*)(ws + off); off = align256(off + (size_t)N_NODES * 64 * 2);
  unsigned short* ab   = (unsigned short*)(ws + off); off = align256(off + (size_t)N_NODES * 64 * 2);
  uint2* csr  = (uint2*)(ws + off); off = align256(off + (size_t)N_EDGES * 8);
  int* deg    = (int*)(ws + off); off = align256(off + (size_t)N_NODES * 4);
  int* offs   = (int*)(ws + off); off = align256(off + (size_t)N_NODES * 4);
  int* cursor = (int*)(ws + off); off = align256(off + (size_t)N_NODES * 4);
  int* bsums  = (int*)(ws + off); off = align256(off + 1024);

  const int NB_SCAN = (N_NODES + 255) / 256;  // 196

  hipMemsetAsync(deg, 0, (size_t)N_NODES * 4, stream);

  k_proj<<<(N_NODES * 64 + 255) / 256, 256, 0, stream>>>(x, Wp, bp, hb0);
  k_hist<<<(N_EDGES + 255) / 256, 256, 0, stream>>>(ei, deg);
  k_scan1<<<NB_SCAN, 256, 0, stream>>>(deg, offs, bsums);
  k_scan2<<<1, 256, 0, stream>>>(bsums, NB_SCAN);
  k_scan3<<<NB_SCAN, 256, 0, stream>>>(offs, bsums, cursor);
  k_fill<<<(N_EDGES + 255) / 256, 256, 0, stream>>>(ei, ea, ew1, eb1, ew2, eb2, cursor, csr);

  const int aggGrid = (N_NODES + 31) / 32;  // 8 nodes/wave, 4 waves/block
  const int mlpGrid = 392;
  const int headGrid = ((N_NODES + NPW - 1) / NPW + 3) / 4;

  // layer 0: hb0 -> hb1b
  k_agg<0><<<aggGrid, 256, 0, stream>>>(csr, offs, deg, hb0, ab);
  k_mlp<<<mlpGrid, 256, 0, stream>>>(nw + 0 * 8192, nb + 0 * 64, lng + 0 * 64, lnb + 0 * 64,
                                     hb0, ab, hb1b);
  // layer 1: hb1b -> hb0
  k_agg<1><<<aggGrid, 256, 0, stream>>>(csr, offs, deg, hb1b, ab);
  k_mlp<<<mlpGrid, 256, 0, stream>>>(nw + 1 * 8192, nb + 1 * 64, lng + 1 * 64, lnb + 1 * 64,
                                     hb1b, ab, hb0);
  // layer 2: hb0 -> hb1b
  k_agg<2><<<aggGrid, 256, 0, stream>>>(csr, offs, deg, hb0, ab);
  k_mlp<<<mlpGrid, 256, 0, stream>>>(nw + 2 * 8192, nb + 2 * 64, lng + 2 * 64, lnb + 2 * 64,
                                     hb0, ab, hb1b);

  k_head<<<headGrid, 256, 0, stream>>>(hw1, hb1, hw2, hb2, hb1b, out);
}

// Round 8
// 294.147 us; speedup vs baseline: 2.5239x; 1.0078x over previous
//
#include <hip/hip_runtime.h>
#include <math.h>

#define N_NODES 50000
#define N_EDGES 800000
#define NPW 16          // nodes per wave in head kernel
#define N_STRIPS 3125   // 50000 / 16

typedef __attribute__((ext_vector_type(8))) short bf16x8;
typedef __attribute__((ext_vector_type(4))) float f32x4;
typedef __attribute__((ext_vector_type(2))) float f32x2;

// ---------- helpers ----------
__device__ __forceinline__ float bcast(float v, int lane) {
  return __int_as_float(__builtin_amdgcn_readlane(__float_as_int(v), lane));
}
__device__ __forceinline__ unsigned short f2bf(float f) {  // RNE f32->bf16
  unsigned int u = __float_as_uint(f);
  u += 0x7FFFu + ((u >> 16) & 1u);
  return (unsigned short)(u >> 16);
}
__device__ __forceinline__ float bf2f(unsigned short s) {
  return __uint_as_float(((unsigned int)s) << 16);
}
__device__ __forceinline__ unsigned char f2fp8(float f) {  // e4m3fn (OCP) encode
  return (unsigned char)(__builtin_amdgcn_cvt_pk_fp8_f32(f, f, 0, false) & 0xFF);
}

// ---------- 1. input projection: h = relu(x @ Wp + bp) -> bf16 + fp8 ----------
__global__ __launch_bounds__(256) void k_proj(const float* __restrict__ x,
                                              const float* __restrict__ Wp,
                                              const float* __restrict__ bp,
                                              unsigned short* __restrict__ hb,
                                              unsigned char* __restrict__ h8) {
  int idx = blockIdx.x * 256 + threadIdx.x;
  int n = idx >> 6, j = idx & 63;
  if (n >= N_NODES) return;
  float acc = bp[j];
#pragma unroll
  for (int k = 0; k < 10; k++) acc += x[n * 10 + k] * Wp[k * 64 + j];
  float r = fmaxf(acc, 0.f);
  hb[n * 64 + j] = f2bf(r);
  h8[n * 64 + j] = f2fp8(r);
}

// ---------- 2. CSR build ----------
__global__ __launch_bounds__(256) void k_hist(const int* __restrict__ ei, int* __restrict__ deg) {
  int e = blockIdx.x * 256 + threadIdx.x;
  if (e >= N_EDGES) return;
  atomicAdd(&deg[ei[N_EDGES + e]], 1);
}

__global__ __launch_bounds__(256) void k_scan1(const int* __restrict__ deg,
                                               int* __restrict__ offs,
                                               int* __restrict__ bsums) {
  __shared__ int sm[256];
  int i = blockIdx.x * 256 + threadIdx.x;
  int v = (i < N_NODES) ? deg[i] : 0;
  sm[threadIdx.x] = v;
  __syncthreads();
#pragma unroll
  for (int off = 1; off < 256; off <<= 1) {
    int t = (threadIdx.x >= off) ? sm[threadIdx.x - off] : 0;
    __syncthreads();
    sm[threadIdx.x] += t;
    __syncthreads();
  }
  if (i < N_NODES) offs[i] = sm[threadIdx.x] - v;  // exclusive
  if (threadIdx.x == 255) bsums[blockIdx.x] = sm[255];
}

__global__ __launch_bounds__(256) void k_scan2(int* __restrict__ bsums, int nb) {
  __shared__ int sm[256];
  int t = threadIdx.x;
  int v = (t < nb) ? bsums[t] : 0;
  sm[t] = v;
  __syncthreads();
#pragma unroll
  for (int off = 1; off < 256; off <<= 1) {
    int u = (t >= off) ? sm[t - off] : 0;
    __syncthreads();
    sm[t] += u;
    __syncthreads();
  }
  if (t < nb) bsums[t] = sm[t] - v;  // exclusive
}

__global__ __launch_bounds__(256) void k_scan3(int* __restrict__ offs,
                                               const int* __restrict__ bsums,
                                               int* __restrict__ cursor) {
  int i = blockIdx.x * 256 + threadIdx.x;
  if (i >= N_NODES) return;
  int o = offs[i] + bsums[blockIdx.x];
  offs[i] = o;
  cursor[i] = o;
}

// single-pass fill (known ~58us; cross-XCD line churn floor).
// 8B record: x = src(17b) | q0<<17 (15b) ; y = q1 | q2<<15 (15b each)
__global__ __launch_bounds__(256) void k_fill(const int* __restrict__ ei,
                                              const float* __restrict__ ea,
                                              const float* __restrict__ ew1,
                                              const float* __restrict__ eb1,
                                              const float* __restrict__ ew2,
                                              const float* __restrict__ eb2,
                                              int* __restrict__ cursor,
                                              uint2* __restrict__ csr) {
  int e = blockIdx.x * 256 + threadIdx.x;
  if (e >= N_EDGES) return;
  int s = ei[e];
  int d = ei[N_EDGES + e];
  float a0 = ea[e * 3 + 0], a1 = ea[e * 3 + 1], a2 = ea[e * 3 + 2];
  int q[3];
#pragma unroll
  for (int l = 0; l < 3; l++) {
    float z = eb2[l];
#pragma unroll
    for (int t = 0; t < 16; t++) {
      float hd = a0 * ew1[l * 48 + t] + a1 * ew1[l * 48 + 16 + t] +
                 a2 * ew1[l * 48 + 32 + t] + eb1[l * 16 + t];
      z += fmaxf(hd, 0.f) * ew2[l * 16 + t];
    }
    float w = 1.f / (1.f + __expf(-z));
    q[l] = __float2int_rn(w * 32767.f);
  }
  unsigned int w0 = (unsigned int)s | ((unsigned int)q[0] << 17);
  unsigned int w1 = (unsigned int)q[1] | ((unsigned int)q[2] << 15);
  int pos = atomicAdd(&cursor[d], 1);
  csr[pos] = make_uint2(w0, w1);
}

template <int LI>
__device__ __forceinline__ float decw(uint2 c) {
  unsigned int q = (LI == 0) ? (c.x >> 17) : (LI == 1) ? (c.y & 0x7FFFu) : (c.y >> 15);
  return (float)q * (1.f / 32767.f);
}

// ---------- 3. aggregation: 8 nodes/wave, 8 lanes/node, fp8 row gathers ----------
// row = 64 fp8 = ONE 64B cacheline; table 3.2MB -> resident in every XCD L2.
template <int LI>
__global__ __launch_bounds__(256, 8) void k_agg(const uint2* __restrict__ csr,
                                                const int* __restrict__ offs,
                                                const int* __restrict__ deg,
                                                const unsigned char* __restrict__ h8in,
                                                unsigned short* __restrict__ ab) {
  int lane = threadIdx.x & 63;
  int sub = lane >> 3;   // node slot 0..7
  int jj = lane & 7;     // feature octet: features [8jj, 8jj+8)
  int gw = (blockIdx.x * 256 + threadIdx.x) >> 6;
  int n = gw * 8 + sub;
  bool active = n < N_NODES;
  int start = active ? offs[n] : 0;
  int d = active ? deg[n] : 0;
  const uint2* hrow = (const uint2*)h8in;  // row n at hrow[n*8 + jj] (8B = 8 fp8)
  float a0 = 0.f, a1 = 0.f, a2 = 0.f, a3 = 0.f;
  float a4 = 0.f, a5 = 0.f, a6 = 0.f, a7 = 0.f, ws = 0.f;
  int i = 0;
  for (; i + 4 <= d; i += 4) {
    uint2 c0 = csr[start + i + 0];
    uint2 c1 = csr[start + i + 1];
    uint2 c2 = csr[start + i + 2];
    uint2 c3 = csr[start + i + 3];
    uint2 g0 = hrow[(c0.x & 0x1FFFFu) * 8 + jj];
    uint2 g1 = hrow[(c1.x & 0x1FFFFu) * 8 + jj];
    uint2 g2 = hrow[(c2.x & 0x1FFFFu) * 8 + jj];
    uint2 g3 = hrow[(c3.x & 0x1FFFFu) * 8 + jj];
    float w0 = decw<LI>(c0), w1 = decw<LI>(c1), w2 = decw<LI>(c2), w3 = decw<LI>(c3);
#pragma unroll
    for (int k = 0; k < 4; k++) {
      uint2 g = (k == 0) ? g0 : (k == 1) ? g1 : (k == 2) ? g2 : g3;
      float w = (k == 0) ? w0 : (k == 1) ? w1 : (k == 2) ? w2 : w3;
      f32x2 p01 = __builtin_amdgcn_cvt_pk_f32_fp8(g.x, false);
      f32x2 p23 = __builtin_amdgcn_cvt_pk_f32_fp8(g.x, true);
      f32x2 p45 = __builtin_amdgcn_cvt_pk_f32_fp8(g.y, false);
      f32x2 p67 = __builtin_amdgcn_cvt_pk_f32_fp8(g.y, true);
      a0 += p01[0] * w; a1 += p01[1] * w;
      a2 += p23[0] * w; a3 += p23[1] * w;
      a4 += p45[0] * w; a5 += p45[1] * w;
      a6 += p67[0] * w; a7 += p67[1] * w;
    }
    ws += w0 + w1 + w2 + w3;
  }
  for (; i < d; ++i) {
    uint2 c = csr[start + i];
    uint2 g = hrow[(c.x & 0x1FFFFu) * 8 + jj];
    float w = decw<LI>(c);
    f32x2 p01 = __builtin_amdgcn_cvt_pk_f32_fp8(g.x, false);
    f32x2 p23 = __builtin_amdgcn_cvt_pk_f32_fp8(g.x, true);
    f32x2 p45 = __builtin_amdgcn_cvt_pk_f32_fp8(g.y, false);
    f32x2 p67 = __builtin_amdgcn_cvt_pk_f32_fp8(g.y, true);
    a0 += p01[0] * w; a1 += p01[1] * w;
    a2 += p23[0] * w; a3 += p23[1] * w;
    a4 += p45[0] * w; a5 += p45[1] * w;
    a6 += p67[0] * w; a7 += p67[1] * w;
    ws += w;
  }
  if (active) {
    float inv = 1.f / fmaxf(ws, 1e-12f);
    uint4 o;
    o.x = (unsigned int)f2bf(a0 * inv) | ((unsigned int)f2bf(a1 * inv) << 16);
    o.y = (unsigned int)f2bf(a2 * inv) | ((unsigned int)f2bf(a3 * inv) << 16);
    o.z = (unsigned int)f2bf(a4 * inv) | ((unsigned int)f2bf(a5 * inv) << 16);
    o.w = (unsigned int)f2bf(a6 * inv) | ((unsigned int)f2bf(a7 * inv) << 16);
    ((uint4*)ab)[n * 8 + jj] = o;
  }
}

// ---------- 4. node MLP (MFMA) + residual + LayerNorm -> bf16 + fp8 ----------
// C(50000x64) = [hb | ab](50000x128, bf16) @ nw(128x64, cast bf16)
// C/D layout: col=lane&15, row=(lane>>4)*4+reg ; A/B frag: k=(lane>>4)*8+j
__global__ __launch_bounds__(256) void k_mlp(const float* __restrict__ nw,
                                             const float* __restrict__ nb,
                                             const float* __restrict__ g,
                                             const float* __restrict__ b,
                                             const unsigned short* __restrict__ hb_in,
                                             const unsigned short* __restrict__ ab_in,
                                             unsigned short* __restrict__ hbout,
                                             unsigned char* __restrict__ h8out) {
  int lane = threadIdx.x & 63;
  int n16 = lane & 15;
  int q = lane >> 4;
  int wid = (blockIdx.x * 256 + threadIdx.x) >> 6;
  int nwaves = gridDim.x * 4;

  bf16x8 bfr[4][4];
#pragma unroll
  for (int t = 0; t < 4; t++)
#pragma unroll
    for (int kc = 0; kc < 4; kc++) {
      bf16x8 v;
#pragma unroll
      for (int jj = 0; jj < 8; jj++) {
        int k = kc * 32 + q * 8 + jj;
        v[jj] = (short)f2bf(nw[k * 64 + t * 16 + n16]);
      }
      bfr[t][kc] = v;
    }
  float nbv[4], gv[4], bv[4];
#pragma unroll
  for (int t = 0; t < 4; t++) {
    nbv[t] = nb[t * 16 + n16];
    gv[t] = g[t * 16 + n16];
    bv[t] = b[t * 16 + n16];
  }

  for (int s = wid; s < N_STRIPS; s += nwaves) {
    int n0 = s * 16;
    f32x4 acc[4] = {{0.f, 0.f, 0.f, 0.f}, {0.f, 0.f, 0.f, 0.f},
                    {0.f, 0.f, 0.f, 0.f}, {0.f, 0.f, 0.f, 0.f}};
#pragma unroll
    for (int kc = 0; kc < 4; kc++) {
      const unsigned short* base = (kc < 2) ? hb_in : ab_in;
      bf16x8 a = *(const bf16x8*)(base + (size_t)(n0 + n16) * 64 + (kc & 1) * 32 + q * 8);
#pragma unroll
      for (int t = 0; t < 4; t++)
        acc[t] = __builtin_amdgcn_mfma_f32_16x16x32_bf16(a, bfr[t][kc], acc[t], 0, 0, 0);
    }
    float r[4][4];
    float p[4], p2[4];
#pragma unroll
    for (int rg = 0; rg < 4; rg++) { p[rg] = 0.f; p2[rg] = 0.f; }
#pragma unroll
    for (int t = 0; t < 4; t++)
#pragma unroll
      for (int rg = 0; rg < 4; rg++) {
        int row = n0 + q * 4 + rg;
        float hv = bf2f(hb_in[row * 64 + t * 16 + n16]);
        float rr = hv + fmaxf(acc[t][rg] + nbv[t], 0.f);
        r[t][rg] = rr;
        p[rg] += rr;
        p2[rg] += rr * rr;
      }
#pragma unroll
    for (int rg = 0; rg < 4; rg++)
#pragma unroll
      for (int off = 1; off < 16; off <<= 1) {
        p[rg] += __shfl_xor(p[rg], off);
        p2[rg] += __shfl_xor(p2[rg], off);
      }
#pragma unroll
    for (int rg = 0; rg < 4; rg++) {
      float mu = p[rg] * (1.f / 64.f);
      float var = p2[rg] * (1.f / 64.f) - mu * mu;
      float rs = rsqrtf(fmaxf(var, 0.f) + 1e-5f);
      int row = n0 + q * 4 + rg;
#pragma unroll
      for (int t = 0; t < 4; t++) {
        float o = (r[t][rg] - mu) * rs * gv[t] + bv[t];
        hbout[row * 64 + t * 16 + n16] = f2bf(o);
        h8out[row * 64 + t * 16 + n16] = f2fp8(o);
      }
    }
  }
}

// ---------- 5. head: out = relu(h@hw1+hb1)@hw2 + hb2 (bf16 h in) ----------
__global__ __launch_bounds__(256, 2) void k_head(const float* __restrict__ hw1,
                                                 const float* __restrict__ hb1,
                                                 const float* __restrict__ hw2,
                                                 const float* __restrict__ hb2,
                                                 const unsigned short* __restrict__ hin,
                                                 float* __restrict__ out) {
  int j = threadIdx.x & 63;
  int jj = j & 31;
  int gw = (blockIdx.x * 256 + threadIdx.x) >> 6;
  float w1[64];
#pragma unroll
  for (int k = 0; k < 64; k++) w1[k] = hw1[k * 32 + jj];
  float hb1j = hb1[jj];
  float hw2j = hw2[jj];
  float hb2v = hb2[0];
  int n0 = gw * NPW;
  for (int n = n0; n < n0 + NPW; ++n) {
    if (n >= N_NODES) break;
    float hv = bf2f(hin[n * 64 + j]);
    float acc = hb1j;
#pragma unroll
    for (int k = 0; k < 64; k++) acc += bcast(hv, k) * w1[k];
    float z = fmaxf(acc, 0.f) * hw2j;
    if (j >= 32) z = 0.f;  // upper 32 lanes duplicate lower-half columns
#pragma unroll
    for (int off = 32; off; off >>= 1) z += __shfl_xor(z, off);
    if (j == 0) out[n] = z + hb2v;
  }
}

// ---------- launch ----------
static inline size_t align256(size_t x) { return (x + 255) & ~size_t(255); }

extern "C" void kernel_launch(void* const* d_in, const int* in_sizes, int n_in,
                              void* d_out, int out_size, void* d_ws, size_t ws_size,
                              hipStream_t stream) {
  const float* x   = (const float*)d_in[0];
  const int*   ei  = (const int*)d_in[1];
  const float* ea  = (const float*)d_in[2];
  const float* Wp  = (const float*)d_in[3];
  const float* bp  = (const float*)d_in[4];
  const float* ew1 = (const float*)d_in[5];
  const float* eb1 = (const float*)d_in[6];
  const float* ew2 = (const float*)d_in[7];
  const float* eb2 = (const float*)d_in[8];
  const float* nw  = (const float*)d_in[9];
  const float* nb  = (const float*)d_in[10];
  const float* lng = (const float*)d_in[11];
  const float* lnb = (const float*)d_in[12];
  const float* hw1 = (const float*)d_in[13];
  const float* hb1 = (const float*)d_in[14];
  const float* hw2 = (const float*)d_in[15];
  const float* hb2 = (const float*)d_in[16];
  float* out = (float*)d_out;

  char* ws = (char*)d_ws;
  size_t off = 0;
  unsigned short* hb0  = (unsigned short*)(ws + off); off = align256(off + (size_t)N_NODES * 64 * 2);
  unsigned short* hb1b = (unsigned short*)(ws + off); off = align256(off + (size_t)N_NODES * 64 * 2);
  unsigned short* ab   = (unsigned short*)(ws + off); off = align256(off + (size_t)N_NODES * 64 * 2);
  unsigned char* h8_0  = (unsigned char*)(ws + off); off = align256(off + (size_t)N_NODES * 64);
  unsigned char* h8_1  = (unsigned char*)(ws + off); off = align256(off + (size_t)N_NODES * 64);
  uint2* csr  = (uint2*)(ws + off); off = align256(off + (size_t)N_EDGES * 8);
  int* deg    = (int*)(ws + off); off = align256(off + (size_t)N_NODES * 4);
  int* offs   = (int*)(ws + off); off = align256(off + (size_t)N_NODES * 4);
  int* cursor = (int*)(ws + off); off = align256(off + (size_t)N_NODES * 4);
  int* bsums  = (int*)(ws + off); off = align256(off + 1024);

  const int NB_SCAN = (N_NODES + 255) / 256;  // 196

  hipMemsetAsync(deg, 0, (size_t)N_NODES * 4, stream);

  k_proj<<<(N_NODES * 64 + 255) / 256, 256, 0, stream>>>(x, Wp, bp, hb0, h8_0);
  k_hist<<<(N_EDGES + 255) / 256, 256, 0, stream>>>(ei, deg);
  k_scan1<<<NB_SCAN, 256, 0, stream>>>(deg, offs, bsums);
  k_scan2<<<1, 256, 0, stream>>>(bsums, NB_SCAN);
  k_scan3<<<NB_SCAN, 256, 0, stream>>>(offs, bsums, cursor);
  k_fill<<<(N_EDGES + 255) / 256, 256, 0, stream>>>(ei, ea, ew1, eb1, ew2, eb2, cursor, csr);

  const int aggGrid = (N_NODES + 31) / 32;  // 8 nodes/wave, 4 waves/block
  const int mlpGrid = 392;
  const int headGrid = ((N_NODES + NPW - 1) / NPW + 3) / 4;

  // layer 0: hb0 -> hb1b
  k_agg<0><<<aggGrid, 256, 0, stream>>>(csr, offs, deg, h8_0, ab);
  k_mlp<<<mlpGrid, 256, 0, stream>>>(nw + 0 * 8192, nb + 0 * 64, lng + 0 * 64, lnb + 0 * 64,
                                     hb0, ab, hb1b, h8_1);
  // layer 1: hb1b -> hb0
  k_agg<1><<<aggGrid, 256, 0, stream>>>(csr, offs, deg, h8_1, ab);
  k_mlp<<<mlpGrid, 256, 0, stream>>>(nw + 1 * 8192, nb + 1 * 64, lng + 1 * 64, lnb + 1 * 64,
                                     hb1b, ab, hb0, h8_0);
  // layer 2: hb0 -> hb1b
  k_agg<2><<<aggGrid, 256, 0, stream>>>(csr, offs, deg, h8_0, ab);
  k_mlp<<<mlpGrid, 256, 0, stream>>>(nw + 2 * 8192, nb + 2 * 64, lng + 2 * 64, lnb + 2 * 64,
                                     hb0, ab, hb1b, h8_1);

  k_head<<<headGrid, 256, 0, stream>>>(hw1, hb1, hw2, hb2, hb1b, out);
}

// Round 9
// 274.288 us; speedup vs baseline: 2.7066x; 1.0724x over previous
//
#include <hip/hip_runtime.h>
#include <math.h>

#define N_NODES 50000
#define N_EDGES 800000
#define NPW 16          // nodes per wave in head kernel
#define N_STRIPS 3125   // 50000 / 16
#define N_BUCKETS 196   // ceil(50000/256); bucket = dst>>8 (== scan block count)
#define CHUNK_A 2048    // edges per k_fillA block
#define PROJ_BLOCKS 12500  // 50000*64/256

typedef __attribute__((ext_vector_type(8))) short bf16x8;
typedef __attribute__((ext_vector_type(4))) float f32x4;
typedef __attribute__((ext_vector_type(2))) float f32x2;

// ---------- helpers ----------
__device__ __forceinline__ float bcast(float v, int lane) {
  return __int_as_float(__builtin_amdgcn_readlane(__float_as_int(v), lane));
}
__device__ __forceinline__ unsigned short f2bf(float f) {  // RNE f32->bf16
  unsigned int u = __float_as_uint(f);
  u += 0x7FFFu + ((u >> 16) & 1u);
  return (unsigned short)(u >> 16);
}
__device__ __forceinline__ float bf2f(unsigned short s) {
  return __uint_as_float(((unsigned int)s) << 16);
}
__device__ __forceinline__ unsigned char f2fp8(float f) {  // e4m3fn (OCP) encode
  return (unsigned char)(__builtin_amdgcn_cvt_pk_fp8_f32(f, f, 0, false) & 0xFF);
}

// ---------- 1. fused input projection (blocks [0,12500)) + degree histogram ----------
__global__ __launch_bounds__(256) void k_projhist(const float* __restrict__ x,
                                                  const float* __restrict__ Wp,
                                                  const float* __restrict__ bp,
                                                  unsigned short* __restrict__ hb,
                                                  unsigned char* __restrict__ h8,
                                                  const int* __restrict__ ei,
                                                  int* __restrict__ deg) {
  int bid = blockIdx.x;
  if (bid < PROJ_BLOCKS) {
    int idx = bid * 256 + threadIdx.x;
    int n = idx >> 6, j = idx & 63;
    float acc = bp[j];
#pragma unroll
    for (int k = 0; k < 10; k++) acc += x[n * 10 + k] * Wp[k * 64 + j];
    float r = fmaxf(acc, 0.f);
    hb[n * 64 + j] = f2bf(r);
    h8[n * 64 + j] = f2fp8(r);
  } else {
    int e = (bid - PROJ_BLOCKS) * 256 + threadIdx.x;  // 3125*256 == N_EDGES exactly
    atomicAdd(&deg[ei[N_EDGES + e]], 1);
  }
}

// ---------- 2. scan: per-block exclusive scan of deg ----------
__global__ __launch_bounds__(256) void k_scan1(const int* __restrict__ deg,
                                               int* __restrict__ offs,
                                               int* __restrict__ bsums) {
  __shared__ int sm[256];
  int i = blockIdx.x * 256 + threadIdx.x;
  int v = (i < N_NODES) ? deg[i] : 0;
  sm[threadIdx.x] = v;
  __syncthreads();
#pragma unroll
  for (int off = 1; off < 256; off <<= 1) {
    int t = (threadIdx.x >= off) ? sm[threadIdx.x - off] : 0;
    __syncthreads();
    sm[threadIdx.x] += t;
    __syncthreads();
  }
  if (i < N_NODES) offs[i] = sm[threadIdx.x] - v;  // exclusive (local)
  if (threadIdx.x == 255) bsums[blockIdx.x] = sm[255];
}

// scan of bsums (each block redoes the 196-scan in LDS) + add base + bucket cursors
__global__ __launch_bounds__(256) void k_scan23(const int* __restrict__ bsums,
                                                int* __restrict__ offs,
                                                int* __restrict__ bcur) {
  __shared__ int sm[256];
  int t = threadIdx.x;
  int v = (t < N_BUCKETS) ? bsums[t] : 0;
  sm[t] = v;
  __syncthreads();
#pragma unroll
  for (int off = 1; off < 256; off <<= 1) {
    int u = (t >= off) ? sm[t - off] : 0;
    __syncthreads();
    sm[t] += u;
    __syncthreads();
  }
  int base = (blockIdx.x == 0) ? 0 : sm[blockIdx.x - 1];  // exclusive prefix
  int nid = blockIdx.x * 256 + t;
  int val = 0;
  if (nid < N_NODES) {
    val = offs[nid] + base;
    offs[nid] = val;
  }
  if (t == 0) bcur[blockIdx.x] = val;  // final offs[b*256] = bucket write frontier
  if (blockIdx.x == 0 && t == 0) offs[N_NODES] = N_EDGES;  // sentinel for agg
}

// ---------- 3a. fillA: edge MLP + dense bucket append (block-local segments)
// 8B record: x = src(17) | q0(13)<<17 | (dl&3)<<30 ; y = q1(13) | q2(13)<<13 | (dl>>2)<<26
__global__ __launch_bounds__(256) void k_fillA(const int* __restrict__ ei,
                                               const float* __restrict__ ea,
                                               const float* __restrict__ ew1,
                                               const float* __restrict__ eb1,
                                               const float* __restrict__ ew2,
                                               const float* __restrict__ eb2,
                                               int* __restrict__ bcur,
                                               uint2* __restrict__ buf1) {
  __shared__ int lcnt[N_BUCKETS];
  __shared__ int gb[N_BUCKETS];
  for (int i = threadIdx.x; i < N_BUCKETS; i += 256) lcnt[i] = 0;
  __syncthreads();
  int base = blockIdx.x * CHUNK_A;
  uint2 rec[CHUNK_A / 256];
  int bk[CHUNK_A / 256], rk[CHUNK_A / 256];
#pragma unroll
  for (int k = 0; k < CHUNK_A / 256; k++) {
    int e = base + k * 256 + threadIdx.x;
    bk[k] = -1;
    if (e < N_EDGES) {
      int s = ei[e];
      int d = ei[N_EDGES + e];
      float a0 = ea[e * 3 + 0], a1 = ea[e * 3 + 1], a2 = ea[e * 3 + 2];
      int q[3];
#pragma unroll
      for (int l = 0; l < 3; l++) {
        float z = eb2[l];
#pragma unroll
        for (int t = 0; t < 16; t++) {
          float hd = a0 * ew1[l * 48 + t] + a1 * ew1[l * 48 + 16 + t] +
                     a2 * ew1[l * 48 + 32 + t] + eb1[l * 16 + t];
          z += fmaxf(hd, 0.f) * ew2[l * 16 + t];
        }
        float w = 1.f / (1.f + __expf(-z));
        q[l] = __float2int_rn(w * 8191.f);
      }
      unsigned int dl = (unsigned int)(d & 255);
      rec[k].x = (unsigned int)s | ((unsigned int)q[0] << 17) | ((dl & 3u) << 30);
      rec[k].y = (unsigned int)q[1] | ((unsigned int)q[2] << 13) | ((dl >> 2) << 26);
      int b = d >> 8;
      bk[k] = b;
      rk[k] = atomicAdd(&lcnt[b], 1);
    }
  }
  __syncthreads();
  if (threadIdx.x < N_BUCKETS) {
    int c = lcnt[threadIdx.x];
    gb[threadIdx.x] = c ? atomicAdd(&bcur[threadIdx.x], c) : 0;
  }
  __syncthreads();
#pragma unroll
  for (int k = 0; k < CHUNK_A / 256; k++)
    if (bk[k] >= 0) buf1[gb[bk[k]] + rk[k]] = rec[k];
}

// ---------- 3b. fillB: bucket -> exact CSR slot; per-dst cursors in LDS,
// scatter confined to this block's ~32KB window (single-XCD line merging)
__global__ __launch_bounds__(256) void k_fillB(const uint2* __restrict__ buf1,
                                               const int* __restrict__ offs,
                                               uint2* __restrict__ csr) {
  __shared__ int lcur[256];
  __shared__ int sstart, send;
  int b = blockIdx.x;
  int nid = b * 256 + threadIdx.x;
  lcur[threadIdx.x] = (nid < N_NODES) ? offs[nid] : N_EDGES;
  if (threadIdx.x == 0) {
    sstart = offs[b * 256];
    send = (b == N_BUCKETS - 1) ? N_EDGES : offs[(b + 1) * 256];
  }
  __syncthreads();
  for (int p = sstart + threadIdx.x; p < send; p += 256) {
    uint2 rec = buf1[p];
    int dl = (int)((rec.x >> 30) | (((rec.y >> 26) & 63u) << 2));
    int pos = atomicAdd(&lcur[dl], 1);
    csr[pos] = rec;
  }
}

template <int LI>
__device__ __forceinline__ float decw(uint2 c) {
  unsigned int q = (LI == 0) ? ((c.x >> 17) & 0x1FFFu)
                 : (LI == 1) ? (c.y & 0x1FFFu)
                             : ((c.y >> 13) & 0x1FFFu);
  return (float)q * (1.f / 8191.f);
}

// ---------- 4. aggregation: 8 nodes/wave, 8 lanes/node, fp8 row gathers ----------
template <int LI>
__global__ __launch_bounds__(256, 8) void k_agg(const uint2* __restrict__ csr,
                                                const int* __restrict__ offs,
                                                const unsigned char* __restrict__ h8in,
                                                unsigned short* __restrict__ ab) {
  int lane = threadIdx.x & 63;
  int sub = lane >> 3;   // node slot 0..7
  int jj = lane & 7;     // feature octet
  int gw = (blockIdx.x * 256 + threadIdx.x) >> 6;
  int n = gw * 8 + sub;
  bool active = n < N_NODES;
  int start = active ? offs[n] : 0;
  int d = active ? (offs[n + 1] - start) : 0;
  const uint2* hrow = (const uint2*)h8in;  // row n at hrow[n*8 + jj] (8 fp8)
  float a0 = 0.f, a1 = 0.f, a2 = 0.f, a3 = 0.f;
  float a4 = 0.f, a5 = 0.f, a6 = 0.f, a7 = 0.f, ws = 0.f;
  int i = 0;
  for (; i + 4 <= d; i += 4) {
    uint2 c0 = csr[start + i + 0];
    uint2 c1 = csr[start + i + 1];
    uint2 c2 = csr[start + i + 2];
    uint2 c3 = csr[start + i + 3];
    uint2 g0 = hrow[(c0.x & 0x1FFFFu) * 8 + jj];
    uint2 g1 = hrow[(c1.x & 0x1FFFFu) * 8 + jj];
    uint2 g2 = hrow[(c2.x & 0x1FFFFu) * 8 + jj];
    uint2 g3 = hrow[(c3.x & 0x1FFFFu) * 8 + jj];
    float w0 = decw<LI>(c0), w1 = decw<LI>(c1), w2 = decw<LI>(c2), w3 = decw<LI>(c3);
#pragma unroll
    for (int k = 0; k < 4; k++) {
      uint2 g = (k == 0) ? g0 : (k == 1) ? g1 : (k == 2) ? g2 : g3;
      float w = (k == 0) ? w0 : (k == 1) ? w1 : (k == 2) ? w2 : w3;
      f32x2 p01 = __builtin_amdgcn_cvt_pk_f32_fp8(g.x, false);
      f32x2 p23 = __builtin_amdgcn_cvt_pk_f32_fp8(g.x, true);
      f32x2 p45 = __builtin_amdgcn_cvt_pk_f32_fp8(g.y, false);
      f32x2 p67 = __builtin_amdgcn_cvt_pk_f32_fp8(g.y, true);
      a0 += p01[0] * w; a1 += p01[1] * w;
      a2 += p23[0] * w; a3 += p23[1] * w;
      a4 += p45[0] * w; a5 += p45[1] * w;
      a6 += p67[0] * w; a7 += p67[1] * w;
    }
    ws += w0 + w1 + w2 + w3;
  }
  for (; i < d; ++i) {
    uint2 c = csr[start + i];
    uint2 g = hrow[(c.x & 0x1FFFFu) * 8 + jj];
    float w = decw<LI>(c);
    f32x2 p01 = __builtin_amdgcn_cvt_pk_f32_fp8(g.x, false);
    f32x2 p23 = __builtin_amdgcn_cvt_pk_f32_fp8(g.x, true);
    f32x2 p45 = __builtin_amdgcn_cvt_pk_f32_fp8(g.y, false);
    f32x2 p67 = __builtin_amdgcn_cvt_pk_f32_fp8(g.y, true);
    a0 += p01[0] * w; a1 += p01[1] * w;
    a2 += p23[0] * w; a3 += p23[1] * w;
    a4 += p45[0] * w; a5 += p45[1] * w;
    a6 += p67[0] * w; a7 += p67[1] * w;
    ws += w;
  }
  if (active) {
    float inv = 1.f / fmaxf(ws, 1e-12f);
    uint4 o;
    o.x = (unsigned int)f2bf(a0 * inv) | ((unsigned int)f2bf(a1 * inv) << 16);
    o.y = (unsigned int)f2bf(a2 * inv) | ((unsigned int)f2bf(a3 * inv) << 16);
    o.z = (unsigned int)f2bf(a4 * inv) | ((unsigned int)f2bf(a5 * inv) << 16);
    o.w = (unsigned int)f2bf(a6 * inv) | ((unsigned int)f2bf(a7 * inv) << 16);
    ((uint4*)ab)[n * 8 + jj] = o;
  }
}

// ---------- 5. node MLP (MFMA) + residual + LayerNorm -> bf16 + fp8 ----------
// C/D layout: col=lane&15, row=(lane>>4)*4+reg ; A/B frag: k=(lane>>4)*8+j
__global__ __launch_bounds__(256) void k_mlp(const float* __restrict__ nw,
                                             const float* __restrict__ nb,
                                             const float* __restrict__ g,
                                             const float* __restrict__ b,
                                             const unsigned short* __restrict__ hb_in,
                                             const unsigned short* __restrict__ ab_in,
                                             unsigned short* __restrict__ hbout,
                                             unsigned char* __restrict__ h8out) {
  int lane = threadIdx.x & 63;
  int n16 = lane & 15;
  int q = lane >> 4;
  int wid = (blockIdx.x * 256 + threadIdx.x) >> 6;
  int nwaves = gridDim.x * 4;

  bf16x8 bfr[4][4];
#pragma unroll
  for (int t = 0; t < 4; t++)
#pragma unroll
    for (int kc = 0; kc < 4; kc++) {
      bf16x8 v;
#pragma unroll
      for (int jj = 0; jj < 8; jj++) {
        int k = kc * 32 + q * 8 + jj;
        v[jj] = (short)f2bf(nw[k * 64 + t * 16 + n16]);
      }
      bfr[t][kc] = v;
    }
  float nbv[4], gv[4], bv[4];
#pragma unroll
  for (int t = 0; t < 4; t++) {
    nbv[t] = nb[t * 16 + n16];
    gv[t] = g[t * 16 + n16];
    bv[t] = b[t * 16 + n16];
  }

  for (int s = wid; s < N_STRIPS; s += nwaves) {
    int n0 = s * 16;
    f32x4 acc[4] = {{0.f, 0.f, 0.f, 0.f}, {0.f, 0.f, 0.f, 0.f},
                    {0.f, 0.f, 0.f, 0.f}, {0.f, 0.f, 0.f, 0.f}};
#pragma unroll
    for (int kc = 0; kc < 4; kc++) {
      const unsigned short* base = (kc < 2) ? hb_in : ab_in;
      bf16x8 a = *(const bf16x8*)(base + (size_t)(n0 + n16) * 64 + (kc & 1) * 32 + q * 8);
#pragma unroll
      for (int t = 0; t < 4; t++)
        acc[t] = __builtin_amdgcn_mfma_f32_16x16x32_bf16(a, bfr[t][kc], acc[t], 0, 0, 0);
    }
    float r[4][4];
    float p[4], p2[4];
#pragma unroll
    for (int rg = 0; rg < 4; rg++) { p[rg] = 0.f; p2[rg] = 0.f; }
#pragma unroll
    for (int t = 0; t < 4; t++)
#pragma unroll
      for (int rg = 0; rg < 4; rg++) {
        int row = n0 + q * 4 + rg;
        float hv = bf2f(hb_in[row * 64 + t * 16 + n16]);
        float rr = hv + fmaxf(acc[t][rg] + nbv[t], 0.f);
        r[t][rg] = rr;
        p[rg] += rr;
        p2[rg] += rr * rr;
      }
#pragma unroll
    for (int rg = 0; rg < 4; rg++)
#pragma unroll
      for (int off = 1; off < 16; off <<= 1) {
        p[rg] += __shfl_xor(p[rg], off);
        p2[rg] += __shfl_xor(p2[rg], off);
      }
#pragma unroll
    for (int rg = 0; rg < 4; rg++) {
      float mu = p[rg] * (1.f / 64.f);
      float var = p2[rg] * (1.f / 64.f) - mu * mu;
      float rs = rsqrtf(fmaxf(var, 0.f) + 1e-5f);
      int row = n0 + q * 4 + rg;
#pragma unroll
      for (int t = 0; t < 4; t++) {
        float o = (r[t][rg] - mu) * rs * gv[t] + bv[t];
        hbout[row * 64 + t * 16 + n16] = f2bf(o);
        h8out[row * 64 + t * 16 + n16] = f2fp8(o);
      }
    }
  }
}

// ---------- 6. head: out = relu(h@hw1+hb1)@hw2 + hb2 ----------
__global__ __launch_bounds__(256, 2) void k_head(const float* __restrict__ hw1,
                                                 const float* __restrict__ hb1,
                                                 const float* __restrict__ hw2,
                                                 const float* __restrict__ hb2,
                                                 const unsigned short* __restrict__ hin,
                                                 float* __restrict__ out) {
  int j = threadIdx.x & 63;
  int jj = j & 31;
  int gw = (blockIdx.x * 256 + threadIdx.x) >> 6;
  float w1[64];
#pragma unroll
  for (int k = 0; k < 64; k++) w1[k] = hw1[k * 32 + jj];
  float hb1j = hb1[jj];
  float hw2j = hw2[jj];
  float hb2v = hb2[0];
  int n0 = gw * NPW;
  for (int n = n0; n < n0 + NPW; ++n) {
    if (n >= N_NODES) break;
    float hv = bf2f(hin[n * 64 + j]);
    float acc = hb1j;
#pragma unroll
    for (int k = 0; k < 64; k++) acc += bcast(hv, k) * w1[k];
    float z = fmaxf(acc, 0.f) * hw2j;
    if (j >= 32) z = 0.f;
#pragma unroll
    for (int off = 32; off; off >>= 1) z += __shfl_xor(z, off);
    if (j == 0) out[n] = z + hb2v;
  }
}

// ---------- launch ----------
static inline size_t align256(size_t x) { return (x + 255) & ~size_t(255); }

extern "C" void kernel_launch(void* const* d_in, const int* in_sizes, int n_in,
                              void* d_out, int out_size, void* d_ws, size_t ws_size,
                              hipStream_t stream) {
  const float* x   = (const float*)d_in[0];
  const int*   ei  = (const int*)d_in[1];
  const float* ea  = (const float*)d_in[2];
  const float* Wp  = (const float*)d_in[3];
  const float* bp  = (const float*)d_in[4];
  const float* ew1 = (const float*)d_in[5];
  const float* eb1 = (const float*)d_in[6];
  const float* ew2 = (const float*)d_in[7];
  const float* eb2 = (const float*)d_in[8];
  const float* nw  = (const float*)d_in[9];
  const float* nb  = (const float*)d_in[10];
  const float* lng = (const float*)d_in[11];
  const float* lnb = (const float*)d_in[12];
  const float* hw1 = (const float*)d_in[13];
  const float* hb1 = (const float*)d_in[14];
  const float* hw2 = (const float*)d_in[15];
  const float* hb2 = (const float*)d_in[16];
  float* out = (float*)d_out;

  char* ws = (char*)d_ws;
  size_t off = 0;
  unsigned short* hb0  = (unsigned short*)(ws + off); off = align256(off + (size_t)N_NODES * 64 * 2);
  unsigned short* hb1b = (unsigned short*)(ws + off); off = align256(off + (size_t)N_NODES * 64 * 2);
  unsigned short* ab   = (unsigned short*)(ws + off); off = align256(off + (size_t)N_NODES * 64 * 2);
  unsigned char* h8_0  = (unsigned char*)(ws + off); off = align256(off + (size_t)N_NODES * 64);
  unsigned char* h8_1  = (unsigned char*)(ws + off); off = align256(off + (size_t)N_NODES * 64);
  uint2* csr  = (uint2*)(ws + off); off = align256(off + (size_t)N_EDGES * 8);
  uint2* buf1 = (uint2*)(ws + off); off = align256(off + (size_t)N_EDGES * 8);
  int* deg    = (int*)(ws + off); off = align256(off + (size_t)N_NODES * 4);
  int* offs   = (int*)(ws + off); off = align256(off + (size_t)(N_NODES + 1) * 4);
  int* bcur   = (int*)(ws + off); off = align256(off + 1024);
  int* bsums  = (int*)(ws + off); off = align256(off + 1024);

  hipMemsetAsync(deg, 0, (size_t)N_NODES * 4, stream);

  k_projhist<<<PROJ_BLOCKS + N_EDGES / 256, 256, 0, stream>>>(x, Wp, bp, hb0, h8_0, ei, deg);
  k_scan1<<<N_BUCKETS, 256, 0, stream>>>(deg, offs, bsums);
  k_scan23<<<N_BUCKETS, 256, 0, stream>>>(bsums, offs, bcur);
  k_fillA<<<(N_EDGES + CHUNK_A - 1) / CHUNK_A, 256, 0, stream>>>(ei, ea, ew1, eb1, ew2, eb2, bcur, buf1);
  k_fillB<<<N_BUCKETS, 256, 0, stream>>>(buf1, offs, csr);

  const int aggGrid = (N_NODES + 31) / 32;  // 8 nodes/wave, 4 waves/block
  const int mlpGrid = 392;
  const int headGrid = ((N_NODES + NPW - 1) / NPW + 3) / 4;

  // layer 0
  k_agg<0><<<aggGrid, 256, 0, stream>>>(csr, offs, h8_0, ab);
  k_mlp<<<mlpGrid, 256, 0, stream>>>(nw + 0 * 8192, nb + 0 * 64, lng + 0 * 64, lnb + 0 * 64,
                                     hb0, ab, hb1b, h8_1);
  // layer 1
  k_agg<1><<<aggGrid, 256, 0, stream>>>(csr, offs, h8_1, ab);
  k_mlp<<<mlpGrid, 256, 0, stream>>>(nw + 1 * 8192, nb + 1 * 64, lng + 1 * 64, lnb + 1 * 64,
                                     hb1b, ab, hb0, h8_0);
  // layer 2
  k_agg<2><<<aggGrid, 256, 0, stream>>>(csr, offs, h8_0, ab);
  k_mlp<<<mlpGrid, 256, 0, stream>>>(nw + 2 * 8192, nb + 2 * 64, lng + 2 * 64, lnb + 2 * 64,
                                     hb0, ab, hb1b, h8_1);

  k_head<<<headGrid, 256, 0, stream>>>(hw1, hb1, hw2, hb2, hb1b, out);
}

// Round 10
// 240.307 us; speedup vs baseline: 3.0894x; 1.1414x over previous
//
#include <hip/hip_runtime.h>
#include <math.h>

#define N_NODES 50000
#define N_EDGES 800000
#define NPW 16            // nodes per wave in head kernel
#define N_STRIPS 3125     // 50000 / 16
#define N_BUCKETS 196     // ceil(50000/256); bucket = dst>>8
#define CAP_B 6144        // fixed records per bucket segment (mean 4082, +32 sigma)
#define CHUNK_A 2048      // edges per k_fillA block
#define PROJ_BLOCKS 12500 // 50000*64/256

typedef __attribute__((ext_vector_type(8))) short bf16x8;
typedef __attribute__((ext_vector_type(4))) float f32x4;
typedef __attribute__((ext_vector_type(2))) float f32x2;

// ---------- helpers ----------
__device__ __forceinline__ float bcast(float v, int lane) {
  return __int_as_float(__builtin_amdgcn_readlane(__float_as_int(v), lane));
}
__device__ __forceinline__ unsigned short f2bf(float f) {  // RNE f32->bf16
  unsigned int u = __float_as_uint(f);
  u += 0x7FFFu + ((u >> 16) & 1u);
  return (unsigned short)(u >> 16);
}
__device__ __forceinline__ float bf2f(unsigned short s) {
  return __uint_as_float(((unsigned int)s) << 16);
}
__device__ __forceinline__ unsigned char f2fp8(float f) {  // e4m3fn (OCP) encode
  return (unsigned char)(__builtin_amdgcn_cvt_pk_fp8_f32(f, f, 0, false) & 0xFF);
}

// ---------- 1. input projection -> bf16 + fp8; last block inits bucket cursors ----------
__global__ __launch_bounds__(256) void k_proj(const float* __restrict__ x,
                                              const float* __restrict__ Wp,
                                              const float* __restrict__ bp,
                                              unsigned short* __restrict__ hb,
                                              unsigned char* __restrict__ h8,
                                              int* __restrict__ bcur) {
  int bid = blockIdx.x;
  if (bid == PROJ_BLOCKS) {
    if (threadIdx.x < N_BUCKETS) bcur[threadIdx.x] = threadIdx.x * CAP_B;
    return;
  }
  int idx = bid * 256 + threadIdx.x;
  int n = idx >> 6, j = idx & 63;
  float acc = bp[j];
#pragma unroll
  for (int k = 0; k < 10; k++) acc += x[n * 10 + k] * Wp[k * 64 + j];
  float r = fmaxf(acc, 0.f);
  hb[n * 64 + j] = f2bf(r);
  h8[n * 64 + j] = f2fp8(r);
}

// ---------- 2a. fillA: edge MLP + dense append into fixed bucket segments
// 8B record: x = src(17) | q0(13)<<17 | (dl&3)<<30 ; y = q1(13) | q2(13)<<13 | (dl>>2)<<26
__global__ __launch_bounds__(256) void k_fillA(const int* __restrict__ ei,
                                               const float* __restrict__ ea,
                                               const float* __restrict__ ew1,
                                               const float* __restrict__ eb1,
                                               const float* __restrict__ ew2,
                                               const float* __restrict__ eb2,
                                               int* __restrict__ bcur,
                                               uint2* __restrict__ buf1) {
  __shared__ int lcnt[N_BUCKETS];
  __shared__ int gb[N_BUCKETS];
  for (int i = threadIdx.x; i < N_BUCKETS; i += 256) lcnt[i] = 0;
  __syncthreads();
  int base = blockIdx.x * CHUNK_A;
  uint2 rec[CHUNK_A / 256];
  int bk[CHUNK_A / 256], rk[CHUNK_A / 256];
#pragma unroll
  for (int k = 0; k < CHUNK_A / 256; k++) {
    int e = base + k * 256 + threadIdx.x;
    bk[k] = -1;
    if (e < N_EDGES) {
      int s = ei[e];
      int d = ei[N_EDGES + e];
      float a0 = ea[e * 3 + 0], a1 = ea[e * 3 + 1], a2 = ea[e * 3 + 2];
      int q[3];
#pragma unroll
      for (int l = 0; l < 3; l++) {
        float z = eb2[l];
#pragma unroll
        for (int t = 0; t < 16; t++) {
          float hd = a0 * ew1[l * 48 + t] + a1 * ew1[l * 48 + 16 + t] +
                     a2 * ew1[l * 48 + 32 + t] + eb1[l * 16 + t];
          z += fmaxf(hd, 0.f) * ew2[l * 16 + t];
        }
        float w = 1.f / (1.f + __expf(-z));
        q[l] = __float2int_rn(w * 8191.f);
      }
      unsigned int dl = (unsigned int)(d & 255);
      rec[k].x = (unsigned int)s | ((unsigned int)q[0] << 17) | ((dl & 3u) << 30);
      rec[k].y = (unsigned int)q[1] | ((unsigned int)q[2] << 13) | ((dl >> 2) << 26);
      int b = d >> 8;
      bk[k] = b;
      rk[k] = atomicAdd(&lcnt[b], 1);
    }
  }
  __syncthreads();
  if (threadIdx.x < N_BUCKETS) {
    int c = lcnt[threadIdx.x];
    gb[threadIdx.x] = c ? atomicAdd(&bcur[threadIdx.x], c) : 0;
  }
  __syncthreads();
#pragma unroll
  for (int k = 0; k < CHUNK_A / 256; k++)
    if (bk[k] >= 0) buf1[gb[bk[k]] + rk[k]] = rec[k];
}

// ---------- 2b. fillB: block = bucket; LDS histogram + scan -> per-dst offsets,
// then scatter into this bucket's private 48KB csr window (single-XCD merging).
__global__ __launch_bounds__(256) void k_fillB(const uint2* __restrict__ buf1,
                                               const int* __restrict__ bcur,
                                               uint2* __restrict__ csr,
                                               int* __restrict__ aoffs,
                                               int* __restrict__ adeg) {
  __shared__ int lhist[256];
  __shared__ int lscan[256];
  int b = blockIdx.x;
  int t = threadIdx.x;
  int segbase = b * CAP_B;
  int cnt = bcur[b] - segbase;
  lhist[t] = 0;
  __syncthreads();
  for (int i = t; i < cnt; i += 256) {
    uint2 rec = buf1[segbase + i];
    int dl = (int)((rec.x >> 30) | (((rec.y >> 26) & 63u) << 2));
    atomicAdd(&lhist[dl], 1);
  }
  __syncthreads();
  int v = lhist[t];
  lscan[t] = v;
  __syncthreads();
#pragma unroll
  for (int off = 1; off < 256; off <<= 1) {
    int u = (t >= off) ? lscan[t - off] : 0;
    __syncthreads();
    lscan[t] += u;
    __syncthreads();
  }
  int excl = lscan[t] - v;  // exclusive prefix within bucket
  int nid = b * 256 + t;
  if (nid < N_NODES) {
    aoffs[nid] = segbase + excl;
    adeg[nid] = v;
  }
  __syncthreads();
  lhist[t] = segbase + excl;  // reuse as write cursor
  __syncthreads();
  for (int i = t; i < cnt; i += 256) {
    uint2 rec = buf1[segbase + i];
    int dl = (int)((rec.x >> 30) | (((rec.y >> 26) & 63u) << 2));
    int pos = atomicAdd(&lhist[dl], 1);
    csr[pos] = rec;
  }
}

template <int LI>
__device__ __forceinline__ float decw(uint2 c) {
  unsigned int q = (LI == 0) ? ((c.x >> 17) & 0x1FFFu)
                 : (LI == 1) ? (c.y & 0x1FFFu)
                             : ((c.y >> 13) & 0x1FFFu);
  return (float)q * (1.f / 8191.f);
}

// ---------- 3. aggregation: 8 nodes/wave, 8 lanes/node, fp8 row gathers ----------
template <int LI>
__global__ __launch_bounds__(256, 8) void k_agg(const uint2* __restrict__ csr,
                                                const int* __restrict__ aoffs,
                                                const int* __restrict__ adeg,
                                                const unsigned char* __restrict__ h8in,
                                                unsigned short* __restrict__ ab) {
  int lane = threadIdx.x & 63;
  int sub = lane >> 3;   // node slot 0..7
  int jj = lane & 7;     // feature octet
  int gw = (blockIdx.x * 256 + threadIdx.x) >> 6;
  int n = gw * 8 + sub;
  bool active = n < N_NODES;
  int start = active ? aoffs[n] : 0;
  int d = active ? adeg[n] : 0;
  const uint2* hrow = (const uint2*)h8in;  // row n at hrow[n*8 + jj] (8 fp8)
  float a0 = 0.f, a1 = 0.f, a2 = 0.f, a3 = 0.f;
  float a4 = 0.f, a5 = 0.f, a6 = 0.f, a7 = 0.f, ws = 0.f;
  int i = 0;
  for (; i + 4 <= d; i += 4) {
    uint2 c0 = csr[start + i + 0];
    uint2 c1 = csr[start + i + 1];
    uint2 c2 = csr[start + i + 2];
    uint2 c3 = csr[start + i + 3];
    uint2 g0 = hrow[(c0.x & 0x1FFFFu) * 8 + jj];
    uint2 g1 = hrow[(c1.x & 0x1FFFFu) * 8 + jj];
    uint2 g2 = hrow[(c2.x & 0x1FFFFu) * 8 + jj];
    uint2 g3 = hrow[(c3.x & 0x1FFFFu) * 8 + jj];
    float w0 = decw<LI>(c0), w1 = decw<LI>(c1), w2 = decw<LI>(c2), w3 = decw<LI>(c3);
#pragma unroll
    for (int k = 0; k < 4; k++) {
      uint2 g = (k == 0) ? g0 : (k == 1) ? g1 : (k == 2) ? g2 : g3;
      float w = (k == 0) ? w0 : (k == 1) ? w1 : (k == 2) ? w2 : w3;
      f32x2 p01 = __builtin_amdgcn_cvt_pk_f32_fp8(g.x, false);
      f32x2 p23 = __builtin_amdgcn_cvt_pk_f32_fp8(g.x, true);
      f32x2 p45 = __builtin_amdgcn_cvt_pk_f32_fp8(g.y, false);
      f32x2 p67 = __builtin_amdgcn_cvt_pk_f32_fp8(g.y, true);
      a0 += p01[0] * w; a1 += p01[1] * w;
      a2 += p23[0] * w; a3 += p23[1] * w;
      a4 += p45[0] * w; a5 += p45[1] * w;
      a6 += p67[0] * w; a7 += p67[1] * w;
    }
    ws += w0 + w1 + w2 + w3;
  }
  for (; i < d; ++i) {
    uint2 c = csr[start + i];
    uint2 g = hrow[(c.x & 0x1FFFFu) * 8 + jj];
    float w = decw<LI>(c);
    f32x2 p01 = __builtin_amdgcn_cvt_pk_f32_fp8(g.x, false);
    f32x2 p23 = __builtin_amdgcn_cvt_pk_f32_fp8(g.x, true);
    f32x2 p45 = __builtin_amdgcn_cvt_pk_f32_fp8(g.y, false);
    f32x2 p67 = __builtin_amdgcn_cvt_pk_f32_fp8(g.y, true);
    a0 += p01[0] * w; a1 += p01[1] * w;
    a2 += p23[0] * w; a3 += p23[1] * w;
    a4 += p45[0] * w; a5 += p45[1] * w;
    a6 += p67[0] * w; a7 += p67[1] * w;
    ws += w;
  }
  if (active) {
    float inv = 1.f / fmaxf(ws, 1e-12f);
    uint4 o;
    o.x = (unsigned int)f2bf(a0 * inv) | ((unsigned int)f2bf(a1 * inv) << 16);
    o.y = (unsigned int)f2bf(a2 * inv) | ((unsigned int)f2bf(a3 * inv) << 16);
    o.z = (unsigned int)f2bf(a4 * inv) | ((unsigned int)f2bf(a5 * inv) << 16);
    o.w = (unsigned int)f2bf(a6 * inv) | ((unsigned int)f2bf(a7 * inv) << 16);
    ((uint4*)ab)[n * 8 + jj] = o;
  }
}

// ---------- 4. node MLP (MFMA) + residual + LayerNorm -> bf16 + fp8 ----------
// C/D layout: col=lane&15, row=(lane>>4)*4+reg ; A/B frag: k=(lane>>4)*8+j
__global__ __launch_bounds__(256) void k_mlp(const float* __restrict__ nw,
                                             const float* __restrict__ nb,
                                             const float* __restrict__ g,
                                             const float* __restrict__ b,
                                             const unsigned short* __restrict__ hb_in,
                                             const unsigned short* __restrict__ ab_in,
                                             unsigned short* __restrict__ hbout,
                                             unsigned char* __restrict__ h8out) {
  int lane = threadIdx.x & 63;
  int n16 = lane & 15;
  int q = lane >> 4;
  int wid = (blockIdx.x * 256 + threadIdx.x) >> 6;
  int nwaves = gridDim.x * 4;

  bf16x8 bfr[4][4];
#pragma unroll
  for (int t = 0; t < 4; t++)
#pragma unroll
    for (int kc = 0; kc < 4; kc++) {
      bf16x8 v;
#pragma unroll
      for (int jj = 0; jj < 8; jj++) {
        int k = kc * 32 + q * 8 + jj;
        v[jj] = (short)f2bf(nw[k * 64 + t * 16 + n16]);
      }
      bfr[t][kc] = v;
    }
  float nbv[4], gv[4], bv[4];
#pragma unroll
  for (int t = 0; t < 4; t++) {
    nbv[t] = nb[t * 16 + n16];
    gv[t] = g[t * 16 + n16];
    bv[t] = b[t * 16 + n16];
  }

  for (int s = wid; s < N_STRIPS; s += nwaves) {
    int n0 = s * 16;
    f32x4 acc[4] = {{0.f, 0.f, 0.f, 0.f}, {0.f, 0.f, 0.f, 0.f},
                    {0.f, 0.f, 0.f, 0.f}, {0.f, 0.f, 0.f, 0.f}};
#pragma unroll
    for (int kc = 0; kc < 4; kc++) {
      const unsigned short* base = (kc < 2) ? hb_in : ab_in;
      bf16x8 a = *(const bf16x8*)(base + (size_t)(n0 + n16) * 64 + (kc & 1) * 32 + q * 8);
#pragma unroll
      for (int t = 0; t < 4; t++)
        acc[t] = __builtin_amdgcn_mfma_f32_16x16x32_bf16(a, bfr[t][kc], acc[t], 0, 0, 0);
    }
    float r[4][4];
    float p[4], p2[4];
#pragma unroll
    for (int rg = 0; rg < 4; rg++) { p[rg] = 0.f; p2[rg] = 0.f; }
#pragma unroll
    for (int t = 0; t < 4; t++)
#pragma unroll
      for (int rg = 0; rg < 4; rg++) {
        int row = n0 + q * 4 + rg;
        float hv = bf2f(hb_in[row * 64 + t * 16 + n16]);
        float rr = hv + fmaxf(acc[t][rg] + nbv[t], 0.f);
        r[t][rg] = rr;
        p[rg] += rr;
        p2[rg] += rr * rr;
      }
#pragma unroll
    for (int rg = 0; rg < 4; rg++)
#pragma unroll
      for (int off = 1; off < 16; off <<= 1) {
        p[rg] += __shfl_xor(p[rg], off);
        p2[rg] += __shfl_xor(p2[rg], off);
      }
#pragma unroll
    for (int rg = 0; rg < 4; rg++) {
      float mu = p[rg] * (1.f / 64.f);
      float var = p2[rg] * (1.f / 64.f) - mu * mu;
      float rs = rsqrtf(fmaxf(var, 0.f) + 1e-5f);
      int row = n0 + q * 4 + rg;
#pragma unroll
      for (int t = 0; t < 4; t++) {
        float o = (r[t][rg] - mu) * rs * gv[t] + bv[t];
        hbout[row * 64 + t * 16 + n16] = f2bf(o);
        h8out[row * 64 + t * 16 + n16] = f2fp8(o);
      }
    }
  }
}

// ---------- 5. head: out = relu(h@hw1+hb1)@hw2 + hb2 ----------
__global__ __launch_bounds__(256, 2) void k_head(const float* __restrict__ hw1,
                                                 const float* __restrict__ hb1,
                                                 const float* __restrict__ hw2,
                                                 const float* __restrict__ hb2,
                                                 const unsigned short* __restrict__ hin,
                                                 float* __restrict__ out) {
  int j = threadIdx.x & 63;
  int jj = j & 31;
  int gw = (blockIdx.x * 256 + threadIdx.x) >> 6;
  float w1[64];
#pragma unroll
  for (int k = 0; k < 64; k++) w1[k] = hw1[k * 32 + jj];
  float hb1j = hb1[jj];
  float hw2j = hw2[jj];
  float hb2v = hb2[0];
  int n0 = gw * NPW;
  for (int n = n0; n < n0 + NPW; ++n) {
    if (n >= N_NODES) break;
    float hv = bf2f(hin[n * 64 + j]);
    float acc = hb1j;
#pragma unroll
    for (int k = 0; k < 64; k++) acc += bcast(hv, k) * w1[k];
    float z = fmaxf(acc, 0.f) * hw2j;
    if (j >= 32) z = 0.f;
#pragma unroll
    for (int off = 32; off; off >>= 1) z += __shfl_xor(z, off);
    if (j == 0) out[n] = z + hb2v;
  }
}

// ---------- launch ----------
static inline size_t align256(size_t x) { return (x + 255) & ~size_t(255); }

extern "C" void kernel_launch(void* const* d_in, const int* in_sizes, int n_in,
                              void* d_out, int out_size, void* d_ws, size_t ws_size,
                              hipStream_t stream) {
  const float* x   = (const float*)d_in[0];
  const int*   ei  = (const int*)d_in[1];
  const float* ea  = (const float*)d_in[2];
  const float* Wp  = (const float*)d_in[3];
  const float* bp  = (const float*)d_in[4];
  const float* ew1 = (const float*)d_in[5];
  const float* eb1 = (const float*)d_in[6];
  const float* ew2 = (const float*)d_in[7];
  const float* eb2 = (const float*)d_in[8];
  const float* nw  = (const float*)d_in[9];
  const float* nb  = (const float*)d_in[10];
  const float* lng = (const float*)d_in[11];
  const float* lnb = (const float*)d_in[12];
  const float* hw1 = (const float*)d_in[13];
  const float* hb1 = (const float*)d_in[14];
  const float* hw2 = (const float*)d_in[15];
  const float* hb2 = (const float*)d_in[16];
  float* out = (float*)d_out;

  char* ws = (char*)d_ws;
  size_t off = 0;
  unsigned short* hb0  = (unsigned short*)(ws + off); off = align256(off + (size_t)N_NODES * 64 * 2);
  unsigned short* hb1b = (unsigned short*)(ws + off); off = align256(off + (size_t)N_NODES * 64 * 2);
  unsigned short* ab   = (unsigned short*)(ws + off); off = align256(off + (size_t)N_NODES * 64 * 2);
  unsigned char* h8_0  = (unsigned char*)(ws + off); off = align256(off + (size_t)N_NODES * 64);
  unsigned char* h8_1  = (unsigned char*)(ws + off); off = align256(off + (size_t)N_NODES * 64);
  uint2* csr  = (uint2*)(ws + off); off = align256(off + (size_t)N_BUCKETS * CAP_B * 8);
  uint2* buf1 = (uint2*)(ws + off); off = align256(off + (size_t)N_BUCKETS * CAP_B * 8);
  int* aoffs  = (int*)(ws + off); off = align256(off + (size_t)N_NODES * 4);
  int* adeg   = (int*)(ws + off); off = align256(off + (size_t)N_NODES * 4);
  int* bcur   = (int*)(ws + off); off = align256(off + 1024);

  k_proj<<<PROJ_BLOCKS + 1, 256, 0, stream>>>(x, Wp, bp, hb0, h8_0, bcur);
  k_fillA<<<(N_EDGES + CHUNK_A - 1) / CHUNK_A, 256, 0, stream>>>(ei, ea, ew1, eb1, ew2, eb2, bcur, buf1);
  k_fillB<<<N_BUCKETS, 256, 0, stream>>>(buf1, bcur, csr, aoffs, adeg);

  const int aggGrid = (N_NODES + 31) / 32;  // 8 nodes/wave, 4 waves/block
  const int mlpGrid = 392;
  const int headGrid = ((N_NODES + NPW - 1) / NPW + 3) / 4;

  // layer 0
  k_agg<0><<<aggGrid, 256, 0, stream>>>(csr, aoffs, adeg, h8_0, ab);
  k_mlp<<<mlpGrid, 256, 0, stream>>>(nw + 0 * 8192, nb + 0 * 64, lng + 0 * 64, lnb + 0 * 64,
                                     hb0, ab, hb1b, h8_1);
  // layer 1
  k_agg<1><<<aggGrid, 256, 0, stream>>>(csr, aoffs, adeg, h8_1, ab);
  k_mlp<<<mlpGrid, 256, 0, stream>>>(nw + 1 * 8192, nb + 1 * 64, lng + 1 * 64, lnb + 1 * 64,
                                     hb1b, ab, hb0, h8_0);
  // layer 2
  k_agg<2><<<aggGrid, 256, 0, stream>>>(csr, aoffs, adeg, h8_0, ab);
  k_mlp<<<mlpGrid, 256, 0, stream>>>(nw + 2 * 8192, nb + 2 * 64, lng + 2 * 64, lnb + 2 * 64,
                                     hb0, ab, hb1b, h8_1);

  k_head<<<headGrid, 256, 0, stream>>>(hw1, hb1, hw2, hb2, hb1b, out);
}

// Round 11
// 223.310 us; speedup vs baseline: 3.3245x; 1.0761x over previous
//
#include <hip/hip_runtime.h>
#include <math.h>

#define N_NODES 50000
#define N_EDGES 800000
#define N_STRIPS 3125     // 50000 / 16
#define N_BUCKETS 196     // ceil(50000/256); bucket = dst>>8
#define CAP_B 6144        // fixed records per bucket segment
#define CHUNK_A 2048      // edges per k_fillA block
#define PROJ_BLOCKS 12500 // 50000*64/256

typedef __attribute__((ext_vector_type(8))) short bf16x8;
typedef __attribute__((ext_vector_type(4))) float f32x4;
typedef __attribute__((ext_vector_type(2))) float f32x2;

// ---------- helpers ----------
__device__ __forceinline__ unsigned short f2bf(float f) {  // RNE f32->bf16
  unsigned int u = __float_as_uint(f);
  u += 0x7FFFu + ((u >> 16) & 1u);
  return (unsigned short)(u >> 16);
}
__device__ __forceinline__ float bf2f(unsigned short s) {
  return __uint_as_float(((unsigned int)s) << 16);
}
__device__ __forceinline__ unsigned char f2fp8(float f) {  // e4m3fn (OCP) encode
  return (unsigned char)(__builtin_amdgcn_cvt_pk_fp8_f32(f, f, 0, false) & 0xFF);
}

// ---------- 1. input projection -> bf16 + fp8; extra block inits cursors ----------
__global__ __launch_bounds__(256) void k_proj(const float* __restrict__ x,
                                              const float* __restrict__ Wp,
                                              const float* __restrict__ bp,
                                              unsigned short* __restrict__ hb,
                                              unsigned char* __restrict__ h8,
                                              int* __restrict__ bcur,
                                              int* __restrict__ ocnt,
                                              int* __restrict__ ocur) {
  int bid = blockIdx.x;
  if (bid == PROJ_BLOCKS) {
    if (threadIdx.x < N_BUCKETS) bcur[threadIdx.x] = threadIdx.x * CAP_B;
    if (threadIdx.x < 8) { ocnt[threadIdx.x] = 0; ocur[threadIdx.x] = 0; }
    return;
  }
  int idx = bid * 256 + threadIdx.x;
  int n = idx >> 6, j = idx & 63;
  float acc = bp[j];
#pragma unroll
  for (int k = 0; k < 10; k++) acc += x[n * 10 + k] * Wp[k * 64 + j];
  float r = fmaxf(acc, 0.f);
  hb[n * 64 + j] = f2bf(r);
  h8[n * 64 + j] = f2fp8(r);
}

// ---------- 2a. fillA: edge MLP + dense append into fixed bucket segments
// 8B record: x = src(17) | q0(13)<<17 | (dl&3)<<30 ; y = q1(13) | q2(13)<<13 | (dl>>2)<<26
__global__ __launch_bounds__(256) void k_fillA(const int* __restrict__ ei,
                                               const float* __restrict__ ea,
                                               const float* __restrict__ ew1,
                                               const float* __restrict__ eb1,
                                               const float* __restrict__ ew2,
                                               const float* __restrict__ eb2,
                                               int* __restrict__ bcur,
                                               uint2* __restrict__ buf1) {
  __shared__ int lcnt[N_BUCKETS];
  __shared__ int gb[N_BUCKETS];
  for (int i = threadIdx.x; i < N_BUCKETS; i += 256) lcnt[i] = 0;
  __syncthreads();
  int base = blockIdx.x * CHUNK_A;
  uint2 rec[CHUNK_A / 256];
  int bk[CHUNK_A / 256], rk[CHUNK_A / 256];
#pragma unroll
  for (int k = 0; k < CHUNK_A / 256; k++) {
    int e = base + k * 256 + threadIdx.x;
    bk[k] = -1;
    if (e < N_EDGES) {
      int s = ei[e];
      int d = ei[N_EDGES + e];
      float a0 = ea[e * 3 + 0], a1 = ea[e * 3 + 1], a2 = ea[e * 3 + 2];
      int q[3];
#pragma unroll
      for (int l = 0; l < 3; l++) {
        float z = eb2[l];
#pragma unroll
        for (int t = 0; t < 16; t++) {
          float hd = a0 * ew1[l * 48 + t] + a1 * ew1[l * 48 + 16 + t] +
                     a2 * ew1[l * 48 + 32 + t] + eb1[l * 16 + t];
          z += fmaxf(hd, 0.f) * ew2[l * 16 + t];
        }
        float w = 1.f / (1.f + __expf(-z));
        q[l] = __float2int_rn(w * 8191.f);
      }
      unsigned int dl = (unsigned int)(d & 255);
      rec[k].x = (unsigned int)s | ((unsigned int)q[0] << 17) | ((dl & 3u) << 30);
      rec[k].y = (unsigned int)q[1] | ((unsigned int)q[2] << 13) | ((dl >> 2) << 26);
      int b = d >> 8;
      bk[k] = b;
      rk[k] = atomicAdd(&lcnt[b], 1);
    }
  }
  __syncthreads();
  if (threadIdx.x < N_BUCKETS) {
    int c = lcnt[threadIdx.x];
    gb[threadIdx.x] = c ? atomicAdd(&bcur[threadIdx.x], c) : 0;
  }
  __syncthreads();
#pragma unroll
  for (int k = 0; k < CHUNK_A / 256; k++)
    if (bk[k] >= 0) buf1[gb[bk[k]] + rk[k]] = rec[k];
}

// ---------- 2b. fillB: block = bucket; LDS histogram + scan -> per-dst offsets,
// scatter into private csr window; also accumulate global degree-class counts.
__global__ __launch_bounds__(256) void k_fillB(const uint2* __restrict__ buf1,
                                               const int* __restrict__ bcur,
                                               uint2* __restrict__ csr,
                                               int* __restrict__ aoffs,
                                               int* __restrict__ adeg,
                                               int* __restrict__ ocnt) {
  __shared__ int lhist[256];
  __shared__ int lscan[256];
  __shared__ int lcls[8];
  int b = blockIdx.x;
  int t = threadIdx.x;
  int segbase = b * CAP_B;
  int cnt = bcur[b] - segbase;
  lhist[t] = 0;
  if (t < 8) lcls[t] = 0;
  __syncthreads();
  for (int i = t; i < cnt; i += 256) {
    uint2 rec = buf1[segbase + i];
    int dl = (int)((rec.x >> 30) | (((rec.y >> 26) & 63u) << 2));
    atomicAdd(&lhist[dl], 1);
  }
  __syncthreads();
  int v = lhist[t];
  lscan[t] = v;
  __syncthreads();
#pragma unroll
  for (int off = 1; off < 256; off <<= 1) {
    int u = (t >= off) ? lscan[t - off] : 0;
    __syncthreads();
    lscan[t] += u;
    __syncthreads();
  }
  int excl = lscan[t] - v;
  int nid = b * 256 + t;
  if (nid < N_NODES) {
    aoffs[nid] = segbase + excl;
    adeg[nid] = v;
    atomicAdd(&lcls[min(v >> 2, 7)], 1);
  }
  __syncthreads();
  if (t < 8 && lcls[t]) atomicAdd(&ocnt[t], lcls[t]);
  lhist[t] = segbase + excl;  // reuse as write cursor
  __syncthreads();
  for (int i = t; i < cnt; i += 256) {
    uint2 rec = buf1[segbase + i];
    int dl = (int)((rec.x >> 30) | (((rec.y >> 26) & 63u) << 2));
    int pos = atomicAdd(&lhist[dl], 1);
    csr[pos] = rec;
  }
}

// ---------- 2c. order: group node ids by degree class (width-4 classes) ----------
__global__ __launch_bounds__(256) void k_order(const int* __restrict__ adeg,
                                               const int* __restrict__ ocnt,
                                               int* __restrict__ ocur,
                                               int* __restrict__ order) {
  __shared__ int lc[8], gb[8];
  int t = threadIdx.x;
  int nid = blockIdx.x * 256 + t;
  if (t < 8) lc[t] = 0;
  __syncthreads();
  int cls = 0, rank = 0;
  bool act = nid < N_NODES;
  if (act) {
    cls = min(adeg[nid] >> 2, 7);
    rank = atomicAdd(&lc[cls], 1);
  }
  __syncthreads();
  if (t < 8) {
    int base = 0;
#pragma unroll
    for (int c = 0; c < 8; c++) base += (c < t) ? ocnt[c] : 0;
    int c = lc[t];
    gb[t] = base + (c ? atomicAdd(&ocur[t], c) : 0);
  }
  __syncthreads();
  if (act) order[gb[cls] + rank] = nid;
}

template <int LI>
__device__ __forceinline__ float decw(uint2 c) {
  unsigned int q = (LI == 0) ? ((c.x >> 17) & 0x1FFFu)
                 : (LI == 1) ? (c.y & 0x1FFFu)
                             : ((c.y >> 13) & 0x1FFFu);
  return (float)q * (1.f / 8191.f);
}

// ---------- 3. aggregation: 8 nodes/wave (degree-class-grouped), fp8 gathers ----------
template <int LI>
__global__ __launch_bounds__(256, 8) void k_agg(const uint2* __restrict__ csr,
                                                const int* __restrict__ aoffs,
                                                const int* __restrict__ adeg,
                                                const int* __restrict__ order,
                                                const unsigned char* __restrict__ h8in,
                                                unsigned short* __restrict__ ab) {
  int lane = threadIdx.x & 63;
  int sub = lane >> 3;   // node slot 0..7
  int jj = lane & 7;     // feature octet
  int gw = (blockIdx.x * 256 + threadIdx.x) >> 6;
  int idx = gw * 8 + sub;
  bool active = idx < N_NODES;
  int n = active ? order[idx] : 0;
  int start = active ? aoffs[n] : 0;
  int d = active ? adeg[n] : 0;
  const uint2* hrow = (const uint2*)h8in;  // row n at hrow[n*8 + jj] (8 fp8)
  float a0 = 0.f, a1 = 0.f, a2 = 0.f, a3 = 0.f;
  float a4 = 0.f, a5 = 0.f, a6 = 0.f, a7 = 0.f, ws = 0.f;
  int i = 0;
  for (; i + 4 <= d; i += 4) {
    uint2 c0 = csr[start + i + 0];
    uint2 c1 = csr[start + i + 1];
    uint2 c2 = csr[start + i + 2];
    uint2 c3 = csr[start + i + 3];
    uint2 g0 = hrow[(c0.x & 0x1FFFFu) * 8 + jj];
    uint2 g1 = hrow[(c1.x & 0x1FFFFu) * 8 + jj];
    uint2 g2 = hrow[(c2.x & 0x1FFFFu) * 8 + jj];
    uint2 g3 = hrow[(c3.x & 0x1FFFFu) * 8 + jj];
    float w0 = decw<LI>(c0), w1 = decw<LI>(c1), w2 = decw<LI>(c2), w3 = decw<LI>(c3);
#pragma unroll
    for (int k = 0; k < 4; k++) {
      uint2 g = (k == 0) ? g0 : (k == 1) ? g1 : (k == 2) ? g2 : g3;
      float w = (k == 0) ? w0 : (k == 1) ? w1 : (k == 2) ? w2 : w3;
      f32x2 p01 = __builtin_amdgcn_cvt_pk_f32_fp8(g.x, false);
      f32x2 p23 = __builtin_amdgcn_cvt_pk_f32_fp8(g.x, true);
      f32x2 p45 = __builtin_amdgcn_cvt_pk_f32_fp8(g.y, false);
      f32x2 p67 = __builtin_amdgcn_cvt_pk_f32_fp8(g.y, true);
      a0 += p01[0] * w; a1 += p01[1] * w;
      a2 += p23[0] * w; a3 += p23[1] * w;
      a4 += p45[0] * w; a5 += p45[1] * w;
      a6 += p67[0] * w; a7 += p67[1] * w;
    }
    ws += w0 + w1 + w2 + w3;
  }
  for (; i < d; ++i) {
    uint2 c = csr[start + i];
    uint2 g = hrow[(c.x & 0x1FFFFu) * 8 + jj];
    float w = decw<LI>(c);
    f32x2 p01 = __builtin_amdgcn_cvt_pk_f32_fp8(g.x, false);
    f32x2 p23 = __builtin_amdgcn_cvt_pk_f32_fp8(g.x, true);
    f32x2 p45 = __builtin_amdgcn_cvt_pk_f32_fp8(g.y, false);
    f32x2 p67 = __builtin_amdgcn_cvt_pk_f32_fp8(g.y, true);
    a0 += p01[0] * w; a1 += p01[1] * w;
    a2 += p23[0] * w; a3 += p23[1] * w;
    a4 += p45[0] * w; a5 += p45[1] * w;
    a6 += p67[0] * w; a7 += p67[1] * w;
    ws += w;
  }
  if (active) {
    float inv = 1.f / fmaxf(ws, 1e-12f);
    uint4 o;
    o.x = (unsigned int)f2bf(a0 * inv) | ((unsigned int)f2bf(a1 * inv) << 16);
    o.y = (unsigned int)f2bf(a2 * inv) | ((unsigned int)f2bf(a3 * inv) << 16);
    o.z = (unsigned int)f2bf(a4 * inv) | ((unsigned int)f2bf(a5 * inv) << 16);
    o.w = (unsigned int)f2bf(a6 * inv) | ((unsigned int)f2bf(a7 * inv) << 16);
    ((uint4*)ab)[n * 8 + jj] = o;
  }
}

// ---------- 4. node MLP (MFMA) + residual(identity-MFMA) + LayerNorm [+ head] ----------
// C/D layout: col=lane&15, row=(lane>>4)*4+reg ; A/B frag: k=(lane>>4)*8+j
template <bool HEAD>
__global__ __launch_bounds__(256) void k_mlp(const float* __restrict__ nw,
                                             const float* __restrict__ nb,
                                             const float* __restrict__ g,
                                             const float* __restrict__ b,
                                             const unsigned short* __restrict__ hb_in,
                                             const unsigned short* __restrict__ ab_in,
                                             unsigned short* __restrict__ hbout,
                                             unsigned char* __restrict__ h8out,
                                             const float* __restrict__ hw1,
                                             const float* __restrict__ hb1,
                                             const float* __restrict__ hw2,
                                             const float* __restrict__ hb2,
                                             float* __restrict__ out) {
  __shared__ unsigned short lh[4][16 * 72];  // per-wave bf16 tile, stride 72
  int lane = threadIdx.x & 63;
  int n16 = lane & 15;
  int q = lane >> 4;
  int wv = threadIdx.x >> 6;
  int wid = (blockIdx.x * 256 + threadIdx.x) >> 6;
  int nwaves = gridDim.x * 4;

  bf16x8 bfr[4][4];
#pragma unroll
  for (int t = 0; t < 4; t++)
#pragma unroll
    for (int kc = 0; kc < 4; kc++) {
      bf16x8 v;
#pragma unroll
      for (int jj = 0; jj < 8; jj++) {
        int k = kc * 32 + q * 8 + jj;
        v[jj] = (short)f2bf(nw[k * 64 + t * 16 + n16]);
      }
      bfr[t][kc] = v;
    }
  // identity selector fragments: E_p[k][n] = (k == n+16p)
  bf16x8 eye[2];
#pragma unroll
  for (int p = 0; p < 2; p++) {
    bf16x8 v;
#pragma unroll
    for (int jj = 0; jj < 8; jj++)
      v[jj] = ((q * 8 + jj) == (n16 + 16 * p)) ? (short)0x3F80 : (short)0;
    eye[p] = v;
  }
  float nbv[4], gv[4], bv[4];
#pragma unroll
  for (int t = 0; t < 4; t++) {
    nbv[t] = nb[t * 16 + n16];
    gv[t] = g[t * 16 + n16];
    bv[t] = b[t * 16 + n16];
  }
  // head weights (layer 2 only)
  bf16x8 hfr[2][2];
  float hb1v[2], hw2v[2], hb2v = 0.f;
  if (HEAD) {
#pragma unroll
    for (int kc = 0; kc < 2; kc++)
#pragma unroll
      for (int tl = 0; tl < 2; tl++) {
        bf16x8 v;
#pragma unroll
        for (int jj = 0; jj < 8; jj++)
          v[jj] = (short)f2bf(hw1[(kc * 32 + q * 8 + jj) * 32 + tl * 16 + n16]);
        hfr[kc][tl] = v;
      }
#pragma unroll
    for (int tl = 0; tl < 2; tl++) {
      hb1v[tl] = hb1[tl * 16 + n16];
      hw2v[tl] = hw2[tl * 16 + n16];
    }
    hb2v = hb2[0];
  }

  for (int s = wid; s < N_STRIPS; s += nwaves) {
    int n0 = s * 16;
    f32x4 acc[4] = {{0.f, 0.f, 0.f, 0.f}, {0.f, 0.f, 0.f, 0.f},
                    {0.f, 0.f, 0.f, 0.f}, {0.f, 0.f, 0.f, 0.f}};
    bf16x8 afr[4];
#pragma unroll
    for (int kc = 0; kc < 4; kc++) {
      const unsigned short* base = (kc < 2) ? hb_in : ab_in;
      afr[kc] = *(const bf16x8*)(base + (size_t)(n0 + n16) * 64 + (kc & 1) * 32 + q * 8);
#pragma unroll
      for (int t = 0; t < 4; t++)
        acc[t] = __builtin_amdgcn_mfma_f32_16x16x32_bf16(afr[kc], bfr[t][kc], acc[t], 0, 0, 0);
    }
    // residual h in C layout via identity MFMA (exact)
    f32x4 rres[4];
#pragma unroll
    for (int t = 0; t < 4; t++) {
      f32x4 z = {0.f, 0.f, 0.f, 0.f};
      rres[t] = __builtin_amdgcn_mfma_f32_16x16x32_bf16(afr[t >> 1], eye[t & 1], z, 0, 0, 0);
    }
    float r[4][4];
    float p[4], p2[4];
#pragma unroll
    for (int rg = 0; rg < 4; rg++) { p[rg] = 0.f; p2[rg] = 0.f; }
#pragma unroll
    for (int t = 0; t < 4; t++)
#pragma unroll
      for (int rg = 0; rg < 4; rg++) {
        float rr = rres[t][rg] + fmaxf(acc[t][rg] + nbv[t], 0.f);
        r[t][rg] = rr;
        p[rg] += rr;
        p2[rg] += rr * rr;
      }
#pragma unroll
    for (int rg = 0; rg < 4; rg++)
#pragma unroll
      for (int off = 1; off < 16; off <<= 1) {
        p[rg] += __shfl_xor(p[rg], off);
        p2[rg] += __shfl_xor(p2[rg], off);
      }
#pragma unroll
    for (int rg = 0; rg < 4; rg++) {
      float mu = p[rg] * (1.f / 64.f);
      float var = p2[rg] * (1.f / 64.f) - mu * mu;
      float rs = rsqrtf(fmaxf(var, 0.f) + 1e-5f);
      int row = n0 + q * 4 + rg;
#pragma unroll
      for (int t = 0; t < 4; t++) {
        float o = (r[t][rg] - mu) * rs * gv[t] + bv[t];
        unsigned short ob = f2bf(o);
        hbout[row * 64 + t * 16 + n16] = ob;
        h8out[row * 64 + t * 16 + n16] = f2fp8(o);
        if (HEAD) lh[wv][(q * 4 + rg) * 72 + t * 16 + n16] = ob;
      }
    }
    if (HEAD) {
      asm volatile("s_waitcnt lgkmcnt(0)" ::: "memory");  // wave-local LDS RAW
      f32x4 hacc[2] = {{0.f, 0.f, 0.f, 0.f}, {0.f, 0.f, 0.f, 0.f}};
#pragma unroll
      for (int kc = 0; kc < 2; kc++) {
        bf16x8 ha = *(const bf16x8*)&lh[wv][n16 * 72 + kc * 32 + q * 8];
#pragma unroll
        for (int tl = 0; tl < 2; tl++)
          hacc[tl] = __builtin_amdgcn_mfma_f32_16x16x32_bf16(ha, hfr[kc][tl], hacc[tl], 0, 0, 0);
      }
#pragma unroll
      for (int rg = 0; rg < 4; rg++) {
        float sres = fmaxf(hacc[0][rg] + hb1v[0], 0.f) * hw2v[0] +
                     fmaxf(hacc[1][rg] + hb1v[1], 0.f) * hw2v[1];
#pragma unroll
        for (int off = 1; off < 16; off <<= 1) sres += __shfl_xor(sres, off);
        if (n16 == 0) out[n0 + q * 4 + rg] = sres + hb2v;
      }
    }
  }
}

// ---------- launch ----------
static inline size_t align256(size_t x) { return (x + 255) & ~size_t(255); }

extern "C" void kernel_launch(void* const* d_in, const int* in_sizes, int n_in,
                              void* d_out, int out_size, void* d_ws, size_t ws_size,
                              hipStream_t stream) {
  const float* x   = (const float*)d_in[0];
  const int*   ei  = (const int*)d_in[1];
  const float* ea  = (const float*)d_in[2];
  const float* Wp  = (const float*)d_in[3];
  const float* bp  = (const float*)d_in[4];
  const float* ew1 = (const float*)d_in[5];
  const float* eb1 = (const float*)d_in[6];
  const float* ew2 = (const float*)d_in[7];
  const float* eb2 = (const float*)d_in[8];
  const float* nw  = (const float*)d_in[9];
  const float* nb  = (const float*)d_in[10];
  const float* lng = (const float*)d_in[11];
  const float* lnb = (const float*)d_in[12];
  const float* hw1 = (const float*)d_in[13];
  const float* hb1 = (const float*)d_in[14];
  const float* hw2 = (const float*)d_in[15];
  const float* hb2 = (const float*)d_in[16];
  float* out = (float*)d_out;

  char* ws = (char*)d_ws;
  size_t off = 0;
  unsigned short* hb0  = (unsigned short*)(ws + off); off = align256(off + (size_t)N_NODES * 64 * 2);
  unsigned short* hb1b = (unsigned short*)(ws + off); off = align256(off + (size_t)N_NODES * 64 * 2);
  unsigned short* ab   = (unsigned short*)(ws + off); off = align256(off + (size_t)N_NODES * 64 * 2);
  unsigned char* h8_0  = (unsigned char*)(ws + off); off = align256(off + (size_t)N_NODES * 64);
  unsigned char* h8_1  = (unsigned char*)(ws + off); off = align256(off + (size_t)N_NODES * 64);
  uint2* csr  = (uint2*)(ws + off); off = align256(off + (size_t)N_BUCKETS * CAP_B * 8);
  uint2* buf1 = (uint2*)(ws + off); off = align256(off + (size_t)N_BUCKETS * CAP_B * 8);
  int* aoffs  = (int*)(ws + off); off = align256(off + (size_t)N_NODES * 4);
  int* adeg   = (int*)(ws + off); off = align256(off + (size_t)N_NODES * 4);
  int* order  = (int*)(ws + off); off = align256(off + (size_t)N_NODES * 4);
  int* bcur   = (int*)(ws + off); off = align256(off + 1024);
  int* ocnt   = (int*)(ws + off); off = align256(off + 256);
  int* ocur   = (int*)(ws + off); off = align256(off + 256);

  k_proj<<<PROJ_BLOCKS + 1, 256, 0, stream>>>(x, Wp, bp, hb0, h8_0, bcur, ocnt, ocur);
  k_fillA<<<(N_EDGES + CHUNK_A - 1) / CHUNK_A, 256, 0, stream>>>(ei, ea, ew1, eb1, ew2, eb2, bcur, buf1);
  k_fillB<<<N_BUCKETS, 256, 0, stream>>>(buf1, bcur, csr, aoffs, adeg, ocnt);
  k_order<<<N_BUCKETS, 256, 0, stream>>>(adeg, ocnt, ocur, order);

  const int aggGrid = (N_NODES + 31) / 32;  // 8 nodes/wave, 4 waves/block
  const int mlpGrid = 392;

  // layer 0
  k_agg<0><<<aggGrid, 256, 0, stream>>>(csr, aoffs, adeg, order, h8_0, ab);
  k_mlp<false><<<mlpGrid, 256, 0, stream>>>(nw + 0 * 8192, nb + 0 * 64, lng + 0 * 64, lnb + 0 * 64,
                                            hb0, ab, hb1b, h8_1, hw1, hb1, hw2, hb2, out);
  // layer 1
  k_agg<1><<<aggGrid, 256, 0, stream>>>(csr, aoffs, adeg, order, h8_1, ab);
  k_mlp<false><<<mlpGrid, 256, 0, stream>>>(nw + 1 * 8192, nb + 1 * 64, lng + 1 * 64, lnb + 1 * 64,
                                            hb1b, ab, hb0, h8_0, hw1, hb1, hw2, hb2, out);
  // layer 2 + fused head
  k_agg<2><<<aggGrid, 256, 0, stream>>>(csr, aoffs, adeg, order, h8_0, ab);
  k_mlp<true><<<mlpGrid, 256, 0, stream>>>(nw + 2 * 8192, nb + 2 * 64, lng + 2 * 64, lnb + 2 * 64,
                                           hb0, ab, hb1b, h8_1, hw1, hb1, hw2, hb2, out);
}